// Round 1
// baseline (1112.731 us; speedup 1.0000x reference)
//
#include <hip/hip_runtime.h>
#include <math.h>

typedef unsigned short u16;
typedef short s16x8 __attribute__((ext_vector_type(8)));
typedef float f32x4 __attribute__((ext_vector_type(4)));

#define BS_   32768      // B*S
#define SEQ_  4096
#define DM_   512
#define FF_   1024
#define FIN_  586
#define FINP_ 608

__device__ __forceinline__ u16 f2b(float f) {
    union { float f; unsigned u; } a; a.f = f;
    unsigned u = a.u;
    unsigned r = (u + 0x7FFFu + ((u >> 16) & 1u)) >> 16;   // RNE
    return (u16)r;
}
__device__ __forceinline__ float b2f(u16 h) {
    union { unsigned u; float f; } a; a.u = ((unsigned)h) << 16;
    return a.f;
}

// ---------------- weight transpose + bf16 convert:  Wt[n][k] = bf16(W[k][n]) ----------
__global__ void k_tr(const float* __restrict__ W, u16* __restrict__ Wt,
                     int K, int N, int Kpad) {
    __shared__ float t[32][33];
    int kb = blockIdx.x << 5, nb = blockIdx.y << 5;
    int tx = threadIdx.x, ty = threadIdx.y;          // 32 x 8
#pragma unroll
    for (int j = 0; j < 32; j += 8) {
        int k = kb + ty + j;
        t[ty + j][tx] = (k < K) ? W[(size_t)k * N + nb + tx] : 0.f;
    }
    __syncthreads();
#pragma unroll
    for (int j = 0; j < 32; j += 8) {
        Wt[(size_t)(nb + ty + j) * Kpad + kb + tx] = f2b(t[tx][ty + j]);
    }
}

// ---------------- embeddings -> bf16 padded [BS][608] --------------------------------
__global__ void k_emb(const float* __restrict__ E, u16* __restrict__ Ep) {
    int i = blockIdx.x * 256 + threadIdx.x;
    const int total8 = BS_ * (FINP_ / 8);
    for (; i < total8; i += gridDim.x * 256) {
        int rr = i / (FINP_ / 8), c = (i % (FINP_ / 8)) * 8;
        s16x8 o;
#pragma unroll
        for (int e = 0; e < 8; ++e) {
            int cc = c + e;
            float v = (cc < FIN_) ? E[(size_t)rr * FIN_ + cc] : 0.f;
            o[e] = (short)f2b(v);
        }
        *(s16x8*)(Ep + (size_t)rr * FINP_ + c) = o;
    }
}

// ---------------- MFMA GEMM: C[M,N] = A[M,K](bf16) * Bt[N,K]^T(bf16) + epilogue -------
// 128x128 tile, BK=32, 256 thr (4 waves), wave -> 64x64 quadrant, 4x4 frags 16x16x32.
template<int FEAT, int RELU, int RESID, int WF32, int WB16>
__global__ __launch_bounds__(256)
void k_gemm(const u16* __restrict__ A, const u16* __restrict__ Bt,
            const float* __restrict__ bias, const float* __restrict__ resid,
            float* __restrict__ Cf, u16* __restrict__ Cb,
            int M, int N, int K) {
    constexpr int PAD = 40;                       // 80B rows: spreads banks, keeps 16B align
    __shared__ __align__(16) u16 sA[128 * PAD];
    __shared__ __align__(16) u16 sB[128 * PAD];
    const int tid = threadIdx.x;
    const int m0 = blockIdx.y << 7, n0 = blockIdx.x << 7;
    const int w = tid >> 6, l = tid & 63;
    const int wm = (w >> 1) << 6, wn = (w & 1) << 6;
    const int lr = l & 15, lg = l >> 4;

    f32x4 acc[4][4] = {};

    const int srow = tid >> 2, sc8 = (tid & 3) << 3;
    const u16* Ap = A + (size_t)(m0 + srow) * K + sc8;
    const u16* Bp = Bt + (size_t)(n0 + srow) * K + sc8;

    for (int k0 = 0; k0 < K; k0 += 32) {
        s16x8 a0 = *(const s16x8*)(Ap + k0);
        s16x8 a1 = *(const s16x8*)(Ap + (size_t)64 * K + k0);
        s16x8 b0 = *(const s16x8*)(Bp + k0);
        s16x8 b1 = *(const s16x8*)(Bp + (size_t)64 * K + k0);
        *(s16x8*)(sA + srow * PAD + sc8) = a0;
        *(s16x8*)(sA + (srow + 64) * PAD + sc8) = a1;
        *(s16x8*)(sB + srow * PAD + sc8) = b0;
        *(s16x8*)(sB + (srow + 64) * PAD + sc8) = b1;
        __syncthreads();

        s16x8 af[4], bf[4];
#pragma unroll
        for (int i = 0; i < 4; ++i) af[i] = *(const s16x8*)(sA + (wm + i * 16 + lr) * PAD + (lg << 3));
#pragma unroll
        for (int j = 0; j < 4; ++j) bf[j] = *(const s16x8*)(sB + (wn + j * 16 + lr) * PAD + (lg << 3));
#pragma unroll
        for (int i = 0; i < 4; ++i)
#pragma unroll
            for (int j = 0; j < 4; ++j)
                acc[i][j] = __builtin_amdgcn_mfma_f32_16x16x32_bf16(af[i], bf[j], acc[i][j], 0, 0, 0);
        __syncthreads();
    }

    // epilogue: D row = m0+wm+i*16+lg*4+r, col = n0+wn+j*16+lr  (verified gfx950 C/D map)
#pragma unroll
    for (int j = 0; j < 4; ++j) {
        const int col = n0 + wn + j * 16 + lr;
        const float bv = bias[col];
#pragma unroll
        for (int i = 0; i < 4; ++i) {
            const int rowb = m0 + wm + i * 16 + (lg << 2);
#pragma unroll
            for (int r = 0; r < 4; ++r) {
                float v = acc[i][j][r] + bv;
                if constexpr (RESID) v += resid[(size_t)(rowb + r) * N + col];
                if constexpr (RELU) v = fmaxf(v, 0.f);
                if constexpr (FEAT) v = (v > 0.f) ? v + 1.f : __expf(v);   // elu(x)+1
                if constexpr (WF32) Cf[(size_t)(rowb + r) * N + col] = v;
                if constexpr (WB16) Cb[(size_t)(rowb + r) * N + col] = f2b(v);
            }
        }
    }
}

// ---------------- kv einsum: kv[b,h,d,m] = sum_s k*v ; ksum[b,h,d] = sum_s k ----------
// grid (64 bh, 4 s-chunks); block 256; fp32 partials per chunk.
__global__ __launch_bounds__(256)
void k_kv(const u16* __restrict__ kb_, const u16* __restrict__ vb_,
          float* __restrict__ kvp, float* __restrict__ ksump) {
    __shared__ float sk[64 * 68], sv[64 * 68];
    int bh = blockIdx.x, b = bh >> 3, h = bh & 7;
    int ch = blockIdx.y;
    int tid = threadIdx.x;
    int d0 = (tid & 15) << 2, m0 = (tid >> 4) << 2;
    float acc[4][4] = {};
    float ks[4] = {0.f, 0.f, 0.f, 0.f};
    size_t gbase = ((size_t)b * SEQ_ + (size_t)ch * 1024) * DM_ + h * 64;

    for (int st = 0; st < 1024; st += 64) {
#pragma unroll
        for (int i = 0; i < 2; ++i) {
            int li = tid + (i << 8);
            int r = li >> 3, c8 = (li & 7) << 3;
            s16x8 kv_ = *(const s16x8*)(kb_ + gbase + (size_t)(st + r) * DM_ + c8);
            s16x8 vv_ = *(const s16x8*)(vb_ + gbase + (size_t)(st + r) * DM_ + c8);
#pragma unroll
            for (int e = 0; e < 8; ++e) {
                sk[r * 68 + c8 + e] = b2f((u16)kv_[e]);
                sv[r * 68 + c8 + e] = b2f((u16)vv_[e]);
            }
        }
        __syncthreads();
        for (int s = 0; s < 64; ++s) {
            f32x4 kd = *(const f32x4*)(sk + s * 68 + d0);
            f32x4 vm = *(const f32x4*)(sv + s * 68 + m0);
#pragma unroll
            for (int i = 0; i < 4; ++i)
#pragma unroll
                for (int j = 0; j < 4; ++j) acc[i][j] += kd[i] * vm[j];
            if ((tid >> 4) == 0) { ks[0] += kd[0]; ks[1] += kd[1]; ks[2] += kd[2]; ks[3] += kd[3]; }
        }
        __syncthreads();
    }
    float* kvo = kvp + ((size_t)ch * 64 + bh) * 4096;
#pragma unroll
    for (int i = 0; i < 4; ++i)
#pragma unroll
        for (int j = 0; j < 4; ++j) kvo[(d0 + i) * 64 + m0 + j] = acc[i][j];
    if ((tid >> 4) == 0) {
        float* kso = ksump + ((size_t)ch * 64 + bh) * 64;
#pragma unroll
        for (int e = 0; e < 4; ++e) kso[d0 + e] = ks[e];
    }
}

// ---------------- attention apply: a = (q . kv) / (q . ksum + eps) --------------------
// grid (S/64, B*H); block 256 = 64 s-rows x 4 m-groups of 16.
__global__ __launch_bounds__(256)
void k_attn(const u16* __restrict__ qb_, const float* __restrict__ kvp,
            const float* __restrict__ ksump, u16* __restrict__ ab_) {
    __shared__ float skv[64 * 64];
    __shared__ float sq[64 * 65];
    __shared__ float sks[64];
    int tid = threadIdx.x;
    int bh = blockIdx.y, b = bh >> 3, h = bh & 7;
    int s0 = blockIdx.x << 6;

    for (int i = tid; i < 4096; i += 256) {
        float v = 0.f;
#pragma unroll
        for (int c = 0; c < 4; ++c) v += kvp[((size_t)c * 64 + bh) * 4096 + i];
        skv[i] = v;
    }
    if (tid < 64) {
        float v = 0.f;
#pragma unroll
        for (int c = 0; c < 4; ++c) v += ksump[((size_t)c * 64 + bh) * 64 + tid];
        sks[tid] = v;
    }
#pragma unroll
    for (int i = 0; i < 2; ++i) {
        int li = tid + (i << 8);
        int r = li >> 3, c8 = (li & 7) << 3;
        s16x8 v = *(const s16x8*)(qb_ + ((size_t)b * SEQ_ + s0 + r) * DM_ + h * 64 + c8);
#pragma unroll
        for (int e = 0; e < 8; ++e) sq[r * 65 + c8 + e] = b2f((u16)v[e]);
    }
    __syncthreads();

    int sl = tid >> 2, m0 = (tid & 3) << 4;
    float den = 0.f;
    for (int d = 0; d < 64; ++d) den += sq[sl * 65 + d] * sks[d];
    float z = 1.f / (den + 1e-6f);

    float acc[16] = {};
    for (int d = 0; d < 64; ++d) {
        float qv = sq[sl * 65 + d];
        const f32x4* kp = (const f32x4*)(skv + d * 64 + m0);
#pragma unroll
        for (int j4 = 0; j4 < 4; ++j4) {
            f32x4 kv4 = kp[j4];
#pragma unroll
            for (int e = 0; e < 4; ++e) acc[j4 * 4 + e] += qv * kv4[e];
        }
    }
    u16* op = ab_ + ((size_t)b * SEQ_ + s0 + sl) * DM_ + h * 64 + m0;
    s16x8 o0, o1;
#pragma unroll
    for (int e = 0; e < 8; ++e) o0[e] = (short)f2b(acc[e] * z);
#pragma unroll
    for (int e = 0; e < 8; ++e) o1[e] = (short)f2b(acc[8 + e] * z);
    *(s16x8*)op = o0;
    *(s16x8*)(op + 8) = o1;
}

// ---------------- LayerNorm over 512, writes fp32 + bf16 ------------------------------
__global__ __launch_bounds__(256)
void k_ln(const float* __restrict__ in, const float* __restrict__ g,
          const float* __restrict__ be, float* __restrict__ xf, u16* __restrict__ xb) {
    int row = blockIdx.x * 4 + (threadIdx.x >> 6);
    int l = threadIdx.x & 63;
    const f32x4* rp = (const f32x4*)(in + (size_t)row * DM_ + l * 8);
    f32x4 a = rp[0], b = rp[1];
    float sum = a[0] + a[1] + a[2] + a[3] + b[0] + b[1] + b[2] + b[3];
#pragma unroll
    for (int off = 32; off > 0; off >>= 1) sum += __shfl_xor(sum, off);
    float mu = sum * (1.f / DM_);
    float sq = 0.f;
#pragma unroll
    for (int e = 0; e < 4; ++e) { float d = a[e] - mu; sq += d * d; }
#pragma unroll
    for (int e = 0; e < 4; ++e) { float d = b[e] - mu; sq += d * d; }
#pragma unroll
    for (int off = 32; off > 0; off >>= 1) sq += __shfl_xor(sq, off);
    float rs = rsqrtf(sq * (1.f / DM_) + 1e-5f);
    int c = l * 8;
    const f32x4* gp = (const f32x4*)(g + c);
    const f32x4* bp = (const f32x4*)(be + c);
    f32x4 g0 = gp[0], g1 = gp[1], e0 = bp[0], e1 = bp[1];
    f32x4 o0, o1;
    s16x8 pk;
#pragma unroll
    for (int e = 0; e < 4; ++e) { o0[e] = (a[e] - mu) * rs * g0[e] + e0[e]; pk[e] = (short)f2b(o0[e]); }
#pragma unroll
    for (int e = 0; e < 4; ++e) { o1[e] = (b[e] - mu) * rs * g1[e] + e1[e]; pk[4 + e] = (short)f2b(o1[e]); }
    f32x4* xo = (f32x4*)(xf + (size_t)row * DM_ + c);
    xo[0] = o0; xo[1] = o1;
    *(s16x8*)(xb + (size_t)row * DM_ + c) = pk;
}

// ---------------- final LN + dot(Wout) -------------------------------------------------
__global__ __launch_bounds__(256)
void k_final(const float* __restrict__ in, const float* __restrict__ g,
             const float* __restrict__ be, const float* __restrict__ wout,
             const float* __restrict__ bout, float* __restrict__ out) {
    int row = blockIdx.x * 4 + (threadIdx.x >> 6);
    int l = threadIdx.x & 63;
    const f32x4* rp = (const f32x4*)(in + (size_t)row * DM_ + l * 8);
    f32x4 a = rp[0], b = rp[1];
    float sum = a[0] + a[1] + a[2] + a[3] + b[0] + b[1] + b[2] + b[3];
#pragma unroll
    for (int off = 32; off > 0; off >>= 1) sum += __shfl_xor(sum, off);
    float mu = sum * (1.f / DM_);
    float sq = 0.f;
#pragma unroll
    for (int e = 0; e < 4; ++e) { float d = a[e] - mu; sq += d * d; }
#pragma unroll
    for (int e = 0; e < 4; ++e) { float d = b[e] - mu; sq += d * d; }
#pragma unroll
    for (int off = 32; off > 0; off >>= 1) sq += __shfl_xor(sq, off);
    float rs = rsqrtf(sq * (1.f / DM_) + 1e-5f);
    int c = l * 8;
    const f32x4* gp = (const f32x4*)(g + c);
    const f32x4* bp = (const f32x4*)(be + c);
    const f32x4* wp = (const f32x4*)(wout + c);
    f32x4 g0 = gp[0], g1 = gp[1], e0 = bp[0], e1 = bp[1], w0 = wp[0], w1 = wp[1];
    float p = 0.f;
#pragma unroll
    for (int e = 0; e < 4; ++e) p += ((a[e] - mu) * rs * g0[e] + e0[e]) * w0[e];
#pragma unroll
    for (int e = 0; e < 4; ++e) p += ((b[e] - mu) * rs * g1[e] + e1[e]) * w1[e];
#pragma unroll
    for (int off = 32; off > 0; off >>= 1) p += __shfl_xor(p, off);
    if (l == 0) out[row] = p + bout[0];
}

// =======================================================================================
extern "C" void kernel_launch(void* const* d_in, const int* in_sizes, int n_in,
                              void* d_out, int out_size, void* d_ws, size_t ws_size,
                              hipStream_t stream) {
    const float* emb   = (const float*)d_in[0];
    const float* W0    = (const float*)d_in[1];
    const float* b0    = (const float*)d_in[2];
    const float* Wq    = (const float*)d_in[3];
    const float* bq    = (const float*)d_in[4];
    const float* Wk    = (const float*)d_in[5];
    const float* bk    = (const float*)d_in[6];
    const float* Wv    = (const float*)d_in[7];
    const float* bv    = (const float*)d_in[8];
    const float* Wo    = (const float*)d_in[9];
    const float* bo    = (const float*)d_in[10];
    const float* ln1s  = (const float*)d_in[11];
    const float* ln1b  = (const float*)d_in[12];
    const float* W1    = (const float*)d_in[13];
    const float* b1    = (const float*)d_in[14];
    const float* W2    = (const float*)d_in[15];
    const float* b2    = (const float*)d_in[16];
    const float* ln2s  = (const float*)d_in[17];
    const float* ln2b  = (const float*)d_in[18];
    const float* lnfs  = (const float*)d_in[19];
    const float* lnfb  = (const float*)d_in[20];
    const float* Wout  = (const float*)d_in[21];
    const float* bout  = (const float*)d_in[22];
    float* out = (float*)d_out;

    char* ws = (char*)d_ws;
    size_t off = 0;
    auto alloc = [&](size_t bytes) -> void* {
        void* p = ws + off;
        off += (bytes + 255) & ~(size_t)255;
        return p;
    };
    float* r_f  = (float*)alloc((size_t)BS_ * DM_ * 4);   // 64MB; low part doubles as embp
    float* x_f  = (float*)alloc((size_t)BS_ * DM_ * 4);   // 64MB
    u16*  xb    = (u16*)alloc((size_t)BS_ * DM_ * 2);     // 32MB
    u16*  qb    = (u16*)alloc((size_t)BS_ * DM_ * 2);     // 32MB  (h1b = qb..kb, 64MB)
    u16*  kbuf  = (u16*)alloc((size_t)BS_ * DM_ * 2);     // 32MB
    u16*  vbuf  = (u16*)alloc((size_t)BS_ * DM_ * 2);     // 32MB  (ab aliases vbuf)
    float* kvp  = (float*)alloc((size_t)4 * 64 * 4096 * 4);
    float* ksump= (float*)alloc((size_t)4 * 64 * 64 * 4);
    u16*  wp    = (u16*)alloc((size_t)4505600 * 2);       // weight pool ~8.6MB

    u16* embp = (u16*)r_f;    // alias: embp dead before r_f first written
    u16* h1b  = qb;           // alias: qb+kbuf contiguous 64MB
    u16* ab   = vbuf;         // alias: vbuf dead before attn writes

    u16* W0t = wp;            u16* p = wp + 311296;
    u16* Wqt = p; p += 2 * 262144;
    u16* Wkt = p; p += 2 * 262144;
    u16* Wvt = p; p += 2 * 262144;
    u16* Wot = p; p += 2 * 262144;
    u16* W1t = p; p += 2 * 524288;
    u16* W2t = p; p += 2 * 524288;

    dim3 tb(32, 8);
    k_tr<<<dim3(19, 16), tb, 0, stream>>>(W0, W0t, FIN_, DM_, FINP_);
    for (int l = 0; l < 2; ++l) {
        k_tr<<<dim3(16, 16), tb, 0, stream>>>(Wq + (size_t)l * 262144, Wqt + (size_t)l * 262144, 512, 512, 512);
        k_tr<<<dim3(16, 16), tb, 0, stream>>>(Wk + (size_t)l * 262144, Wkt + (size_t)l * 262144, 512, 512, 512);
        k_tr<<<dim3(16, 16), tb, 0, stream>>>(Wv + (size_t)l * 262144, Wvt + (size_t)l * 262144, 512, 512, 512);
        k_tr<<<dim3(16, 16), tb, 0, stream>>>(Wo + (size_t)l * 262144, Wot + (size_t)l * 262144, 512, 512, 512);
        k_tr<<<dim3(16, 32), tb, 0, stream>>>(W1 + (size_t)l * 524288, W1t + (size_t)l * 524288, 512, 1024, 512);
        k_tr<<<dim3(32, 16), tb, 0, stream>>>(W2 + (size_t)l * 524288, W2t + (size_t)l * 524288, 1024, 512, 1024);
    }
    k_emb<<<4096, 256, 0, stream>>>(emb, embp);

    // x = emb @ W0 + b0
    k_gemm<0, 0, 0, 1, 1><<<dim3(4, 256), 256, 0, stream>>>(embp, W0t, b0, nullptr, x_f, xb, BS_, DM_, FINP_);

    for (int l = 0; l < 2; ++l) {
        const size_t wo = (size_t)l * 262144;
        // q,k = feat(x@W+b); v = x@W+b   (bf16 outputs)
        k_gemm<1, 0, 0, 0, 1><<<dim3(4, 256), 256, 0, stream>>>(xb, Wqt + wo, bq + l * 512, nullptr, nullptr, qb, BS_, DM_, DM_);
        k_gemm<1, 0, 0, 0, 1><<<dim3(4, 256), 256, 0, stream>>>(xb, Wkt + wo, bk + l * 512, nullptr, nullptr, kbuf, BS_, DM_, DM_);
        k_gemm<0, 0, 0, 0, 1><<<dim3(4, 256), 256, 0, stream>>>(xb, Wvt + wo, bv + l * 512, nullptr, nullptr, vbuf, BS_, DM_, DM_);
        k_kv<<<dim3(64, 4), 256, 0, stream>>>(kbuf, vbuf, kvp, ksump);
        k_attn<<<dim3(64, 64), 256, 0, stream>>>(qb, kvp, ksump, ab);
        // r = x + a@Wo + bo ; x = LN1(r)
        k_gemm<0, 0, 1, 1, 0><<<dim3(4, 256), 256, 0, stream>>>(ab, Wot + wo, bo + l * 512, x_f, r_f, nullptr, BS_, DM_, DM_);
        k_ln<<<8192, 256, 0, stream>>>(r_f, ln1s + l * 512, ln1b + l * 512, x_f, xb);
        // h = relu(x@W1+b1) ; r = x + h@W2 + b2 ; x = LN2(r)
        k_gemm<0, 1, 0, 0, 1><<<dim3(8, 256), 256, 0, stream>>>(xb, W1t + (size_t)l * 524288, b1 + l * 1024, nullptr, nullptr, h1b, BS_, FF_, DM_);
        k_gemm<0, 0, 1, 1, 0><<<dim3(4, 256), 256, 0, stream>>>(h1b, W2t + (size_t)l * 524288, b2 + l * 512, x_f, r_f, nullptr, BS_, DM_, FF_);
        k_ln<<<8192, 256, 0, stream>>>(r_f, ln2s + l * 512, ln2b + l * 512, x_f, xb);
    }
    k_final<<<8192, 256, 0, stream>>>(x_f, lnfs, lnfb, Wout, bout, out);
}

// Round 2
// 829.645 us; speedup vs baseline: 1.3412x; 1.3412x over previous
//
#include <hip/hip_runtime.h>
#include <math.h>

typedef unsigned short u16;
typedef short s16x8 __attribute__((ext_vector_type(8)));
typedef float f32x4 __attribute__((ext_vector_type(4)));

#define BS_   32768      // B*S
#define SEQ_  4096
#define DM_   512
#define FF_   1024
#define FIN_  586
#define FINP_ 608

__device__ __forceinline__ u16 f2b(float f) {
    union { float f; unsigned u; } a; a.f = f;
    unsigned u = a.u;
    unsigned r = (u + 0x7FFFu + ((u >> 16) & 1u)) >> 16;   // RNE
    return (u16)r;
}
__device__ __forceinline__ float b2f(u16 h) {
    union { unsigned u; float f; } a; a.u = ((unsigned)h) << 16;
    return a.f;
}

typedef __attribute__((address_space(1))) const unsigned gu32;
typedef __attribute__((address_space(3))) unsigned lu32;
__device__ __forceinline__ void glds16(const void* g, void* l) {
    __builtin_amdgcn_global_load_lds((gu32*)g, (lu32*)l, 16, 0, 0);
}

// ---------------- weight transpose + bf16 convert:  Wt[n][k] = bf16(W[k][n]) ----------
__global__ void k_tr(const float* __restrict__ W, u16* __restrict__ Wt,
                     int K, int N, int Kpad) {
    __shared__ float t[32][33];
    int kb = blockIdx.x << 5, nb = blockIdx.y << 5;
    int tx = threadIdx.x, ty = threadIdx.y;          // 32 x 8
#pragma unroll
    for (int j = 0; j < 32; j += 8) {
        int k = kb + ty + j;
        t[ty + j][tx] = (k < K) ? W[(size_t)k * N + nb + tx] : 0.f;
    }
    __syncthreads();
#pragma unroll
    for (int j = 0; j < 32; j += 8) {
        Wt[(size_t)(nb + ty + j) * Kpad + kb + tx] = f2b(t[tx][ty + j]);
    }
}

// ---------------- MFMA GEMM (m97 structure): C = A[M,K] * Bt[N,K]^T + epilogue --------
// 128x128 tile, BK=32, global_load_lds 16B staging, linear LDS, XCD-swizzled 1-D grid.
// EPI: 1 = QKV split (feat on q,k), 2 = residual-add (bf16 resid), 3 = relu
template<int EPI>
__global__ __launch_bounds__(256)
void k_gemm(const u16* __restrict__ A, const u16* __restrict__ Bt,
            const float* __restrict__ bias0, const float* __restrict__ bias1,
            const float* __restrict__ bias2,
            const u16* __restrict__ resid,
            u16* __restrict__ out0, u16* __restrict__ out1, u16* __restrict__ out2,
            int M, int N, int K, int NT) {
    __shared__ __align__(16) u16 sA[128 * 32];
    __shared__ __align__(16) u16 sB[128 * 32];
    const int nwg = gridDim.x;
    const int cpx = nwg >> 3;                       // nwg % 8 == 0 for all our launches
    const int wg = (blockIdx.x & 7) * cpx + (blockIdx.x >> 3);   // XCD-contiguous chunks
    const int mt = wg / NT, nt = wg - mt * NT;      // n-tile fastest -> A shared on-XCD
    const int m0 = mt << 7, n0 = nt << 7;
    const int tid = threadIdx.x;
    const int w = tid >> 6, l = tid & 63;
    const int wm = (w >> 1) << 6, wn = (w & 1) << 6;
    const int lr = l & 15, lg = l >> 4;
    const int srow = tid >> 2, sc8 = (tid & 3) << 3;

    f32x4 acc[4][4] = {};
    const u16* Ap = A + (size_t)(m0 + srow) * K + sc8;
    const u16* Bp = Bt + (size_t)(n0 + srow) * K + sc8;
    u16* sAp = sA + tid * 8;                        // lane-linear: byte off = tid*16
    u16* sBp = sB + tid * 8;

    for (int k0 = 0; k0 < K; k0 += 32) {
        glds16(Ap + k0, sAp);
        glds16(Ap + (size_t)64 * K + k0, sAp + 2048);
        glds16(Bp + k0, sBp);
        glds16(Bp + (size_t)64 * K + k0, sBp + 2048);
        __syncthreads();                            // compiler drains vmcnt(0) here
        s16x8 af[4], bfr[4];
#pragma unroll
        for (int i = 0; i < 4; ++i) af[i] = *(const s16x8*)(sA + (wm + i * 16 + lr) * 32 + (lg << 3));
#pragma unroll
        for (int j = 0; j < 4; ++j) bfr[j] = *(const s16x8*)(sB + (wn + j * 16 + lr) * 32 + (lg << 3));
#pragma unroll
        for (int i = 0; i < 4; ++i)
#pragma unroll
            for (int j = 0; j < 4; ++j)
                acc[i][j] = __builtin_amdgcn_mfma_f32_16x16x32_bf16(af[i], bfr[j], acc[i][j], 0, 0, 0);
        __syncthreads();
    }

    // D map (verified): row = m0+wm+i*16+lg*4+r, col = n0+wn+j*16+lr
    if constexpr (EPI == 1) {
        const int seg = n0 >> 9;                    // 0=q 1=k 2=v (N=1536)
        const float* bias = seg == 0 ? bias0 : (seg == 1 ? bias1 : bias2);
        u16* dst = seg == 0 ? out0 : (seg == 1 ? out1 : out2);
        const int nb = n0 & 511;
#pragma unroll
        for (int j = 0; j < 4; ++j) {
            const int col = nb + wn + j * 16 + lr;
            const float bv = bias[col];
#pragma unroll
            for (int i = 0; i < 4; ++i) {
                const int rowb = m0 + wm + i * 16 + (lg << 2);
#pragma unroll
                for (int r = 0; r < 4; ++r) {
                    float v = acc[i][j][r] + bv;
                    if (seg < 2) v = (v > 0.f) ? v + 1.f : __expf(v);   // elu+1
                    dst[(size_t)(rowb + r) * 512 + col] = f2b(v);
                }
            }
        }
    } else if constexpr (EPI == 2) {
#pragma unroll
        for (int j = 0; j < 4; ++j) {
            const int col = n0 + wn + j * 16 + lr;
            const float bv = bias0[col];
#pragma unroll
            for (int i = 0; i < 4; ++i) {
                const int rowb = m0 + wm + i * 16 + (lg << 2);
#pragma unroll
                for (int r = 0; r < 4; ++r) {
                    float v = acc[i][j][r] + bv + b2f(resid[(size_t)(rowb + r) * N + col]);
                    out0[(size_t)(rowb + r) * N + col] = f2b(v);
                }
            }
        }
    } else {
#pragma unroll
        for (int j = 0; j < 4; ++j) {
            const int col = n0 + wn + j * 16 + lr;
            const float bv = bias0[col];
#pragma unroll
            for (int i = 0; i < 4; ++i) {
                const int rowb = m0 + wm + i * 16 + (lg << 2);
#pragma unroll
                for (int r = 0; r < 4; ++r) {
                    float v = fmaxf(acc[i][j][r] + bv, 0.f);
                    out0[(size_t)(rowb + r) * N + col] = f2b(v);
                }
            }
        }
    }
}

// ---------------- emb GEMM: A fp32 [32768][586] (pad->608), converts while staging ----
__global__ __launch_bounds__(256)
void k_gemm_ef(const float* __restrict__ A, const u16* __restrict__ Bt,
               const float* __restrict__ bias, u16* __restrict__ out, int NT) {
    __shared__ __align__(16) u16 sA[128 * 32];
    __shared__ __align__(16) u16 sB[128 * 32];
    const int nwg = gridDim.x;
    const int cpx = nwg >> 3;
    const int wg = (blockIdx.x & 7) * cpx + (blockIdx.x >> 3);
    const int mt = wg / NT, nt = wg - mt * NT;
    const int m0 = mt << 7, n0 = nt << 7;
    const int tid = threadIdx.x;
    const int w = tid >> 6, l = tid & 63;
    const int wm = (w >> 1) << 6, wn = (w & 1) << 6;
    const int lr = l & 15, lg = l >> 4;
    const int srow = tid >> 2, sc8 = (tid & 3) << 3;

    f32x4 acc[4][4] = {};
    const u16* Bp = Bt + (size_t)(n0 + srow) * FINP_ + sc8;
    u16* sBp = sB + tid * 8;

    for (int k0 = 0; k0 < FINP_; k0 += 32) {
        const int gc = k0 + sc8;
        float av0[8], av1[8];
        const float* a0p = A + (size_t)(m0 + srow) * FIN_ + gc;
        const float* a1p = A + (size_t)(m0 + 64 + srow) * FIN_ + gc;
        if (gc + 7 < FIN_) {
#pragma unroll
            for (int e = 0; e < 8; e += 4) {
                f32x4 t0 = *(const f32x4*)(a0p + e);
                f32x4 t1 = *(const f32x4*)(a1p + e);
#pragma unroll
                for (int q = 0; q < 4; ++q) { av0[e + q] = t0[q]; av1[e + q] = t1[q]; }
            }
        } else {
#pragma unroll
            for (int e = 0; e < 8; ++e) {
                bool ok = (gc + e) < FIN_;
                av0[e] = ok ? a0p[e] : 0.f;
                av1[e] = ok ? a1p[e] : 0.f;
            }
        }
        s16x8 p0, p1;
#pragma unroll
        for (int e = 0; e < 8; ++e) { p0[e] = (short)f2b(av0[e]); p1[e] = (short)f2b(av1[e]); }
        *(s16x8*)(sA + srow * 32 + sc8) = p0;
        *(s16x8*)(sA + (srow + 64) * 32 + sc8) = p1;
        glds16(Bp + k0, sBp);
        glds16(Bp + (size_t)64 * FINP_ + k0, sBp + 2048);
        __syncthreads();
        s16x8 af[4], bfr[4];
#pragma unroll
        for (int i = 0; i < 4; ++i) af[i] = *(const s16x8*)(sA + (wm + i * 16 + lr) * 32 + (lg << 3));
#pragma unroll
        for (int j = 0; j < 4; ++j) bfr[j] = *(const s16x8*)(sB + (wn + j * 16 + lr) * 32 + (lg << 3));
#pragma unroll
        for (int i = 0; i < 4; ++i)
#pragma unroll
            for (int j = 0; j < 4; ++j)
                acc[i][j] = __builtin_amdgcn_mfma_f32_16x16x32_bf16(af[i], bfr[j], acc[i][j], 0, 0, 0);
        __syncthreads();
    }
#pragma unroll
    for (int j = 0; j < 4; ++j) {
        const int col = n0 + wn + j * 16 + lr;
        const float bv = bias[col];
#pragma unroll
        for (int i = 0; i < 4; ++i) {
            const int rowb = m0 + wm + i * 16 + (lg << 2);
#pragma unroll
            for (int r = 0; r < 4; ++r)
                out[(size_t)(rowb + r) * DM_ + col] = f2b(acc[i][j][r] + bv);
        }
    }
}

// ---------------- kv einsum: kv[b,h,d,m] = sum_s k*v ; ksum[b,h,d] = sum_s k ----------
__global__ __launch_bounds__(256)
void k_kv(const u16* __restrict__ kb_, const u16* __restrict__ vb_,
          float* __restrict__ kvp, float* __restrict__ ksump) {
    __shared__ float sk[64 * 68], sv[64 * 68];
    int bh = blockIdx.x, b = bh >> 3, h = bh & 7;
    int ch = blockIdx.y;
    int tid = threadIdx.x;
    int d0 = (tid & 15) << 2, m0 = (tid >> 4) << 2;
    float acc[4][4] = {};
    float ks[4] = {0.f, 0.f, 0.f, 0.f};
    size_t gbase = ((size_t)b * SEQ_ + (size_t)ch * 1024) * DM_ + h * 64;

    for (int st = 0; st < 1024; st += 64) {
#pragma unroll
        for (int i = 0; i < 2; ++i) {
            int li = tid + (i << 8);
            int r = li >> 3, c8 = (li & 7) << 3;
            s16x8 kv_ = *(const s16x8*)(kb_ + gbase + (size_t)(st + r) * DM_ + c8);
            s16x8 vv_ = *(const s16x8*)(vb_ + gbase + (size_t)(st + r) * DM_ + c8);
#pragma unroll
            for (int e = 0; e < 8; ++e) {
                sk[r * 68 + c8 + e] = b2f((u16)kv_[e]);
                sv[r * 68 + c8 + e] = b2f((u16)vv_[e]);
            }
        }
        __syncthreads();
        for (int s = 0; s < 64; ++s) {
            f32x4 kd = *(const f32x4*)(sk + s * 68 + d0);
            f32x4 vm = *(const f32x4*)(sv + s * 68 + m0);
#pragma unroll
            for (int i = 0; i < 4; ++i)
#pragma unroll
                for (int j = 0; j < 4; ++j) acc[i][j] += kd[i] * vm[j];
            if ((tid >> 4) == 0) { ks[0] += kd[0]; ks[1] += kd[1]; ks[2] += kd[2]; ks[3] += kd[3]; }
        }
        __syncthreads();
    }
    float* kvo = kvp + ((size_t)ch * 64 + bh) * 4096;
#pragma unroll
    for (int i = 0; i < 4; ++i)
#pragma unroll
        for (int j = 0; j < 4; ++j) kvo[(d0 + i) * 64 + m0 + j] = acc[i][j];
    if ((tid >> 4) == 0) {
        float* kso = ksump + ((size_t)ch * 64 + bh) * 64;
#pragma unroll
        for (int e = 0; e < 4; ++e) kso[d0 + e] = ks[e];
    }
}

// ---------------- attention apply: a = (q . kv) / (q . ksum + eps) --------------------
__global__ __launch_bounds__(256)
void k_attn(const u16* __restrict__ qb_, const float* __restrict__ kvp,
            const float* __restrict__ ksump, u16* __restrict__ ab_) {
    __shared__ float skv[64 * 64];
    __shared__ float sq[64 * 65];
    __shared__ float sks[64];
    int tid = threadIdx.x;
    int bh = blockIdx.y, b = bh >> 3, h = bh & 7;
    int s0 = blockIdx.x << 6;

    for (int i = tid; i < 4096; i += 256) {
        float v = 0.f;
#pragma unroll
        for (int c = 0; c < 4; ++c) v += kvp[((size_t)c * 64 + bh) * 4096 + i];
        skv[i] = v;
    }
    if (tid < 64) {
        float v = 0.f;
#pragma unroll
        for (int c = 0; c < 4; ++c) v += ksump[((size_t)c * 64 + bh) * 64 + tid];
        sks[tid] = v;
    }
#pragma unroll
    for (int i = 0; i < 2; ++i) {
        int li = tid + (i << 8);
        int r = li >> 3, c8 = (li & 7) << 3;
        s16x8 v = *(const s16x8*)(qb_ + ((size_t)b * SEQ_ + s0 + r) * DM_ + h * 64 + c8);
#pragma unroll
        for (int e = 0; e < 8; ++e) sq[r * 65 + c8 + e] = b2f((u16)v[e]);
    }
    __syncthreads();

    int sl = tid >> 2, m0 = (tid & 3) << 4;
    float den = 0.f;
    for (int d = 0; d < 64; ++d) den += sq[sl * 65 + d] * sks[d];
    float z = 1.f / (den + 1e-6f);

    float acc[16] = {};
    for (int d = 0; d < 64; ++d) {
        float qv = sq[sl * 65 + d];
        const f32x4* kp = (const f32x4*)(skv + d * 64 + m0);
#pragma unroll
        for (int j4 = 0; j4 < 4; ++j4) {
            f32x4 kv4 = kp[j4];
#pragma unroll
            for (int e = 0; e < 4; ++e) acc[j4 * 4 + e] += qv * kv4[e];
        }
    }
    u16* op = ab_ + ((size_t)b * SEQ_ + s0 + sl) * DM_ + h * 64 + m0;
    s16x8 o0, o1;
#pragma unroll
    for (int e = 0; e < 8; ++e) o0[e] = (short)f2b(acc[e] * z);
#pragma unroll
    for (int e = 0; e < 8; ++e) o1[e] = (short)f2b(acc[8 + e] * z);
    *(s16x8*)op = o0;
    *(s16x8*)(op + 8) = o1;
}

// ---------------- LayerNorm over 512 (bf16 in -> bf16 out) ----------------------------
__global__ __launch_bounds__(256)
void k_ln(const u16* __restrict__ in, const float* __restrict__ g,
          const float* __restrict__ be, u16* __restrict__ xb) {
    int row = blockIdx.x * 4 + (threadIdx.x >> 6);
    int l = threadIdx.x & 63;
    s16x8 raw = *(const s16x8*)(in + (size_t)row * DM_ + l * 8);
    float x[8];
#pragma unroll
    for (int e = 0; e < 8; ++e) x[e] = b2f((u16)raw[e]);
    float sum = 0.f;
#pragma unroll
    for (int e = 0; e < 8; ++e) sum += x[e];
#pragma unroll
    for (int off = 32; off > 0; off >>= 1) sum += __shfl_xor(sum, off);
    float mu = sum * (1.f / DM_);
    float sq = 0.f;
#pragma unroll
    for (int e = 0; e < 8; ++e) { float d = x[e] - mu; sq += d * d; }
#pragma unroll
    for (int off = 32; off > 0; off >>= 1) sq += __shfl_xor(sq, off);
    float rs = rsqrtf(sq * (1.f / DM_) + 1e-5f);
    int c = l * 8;
    const f32x4* gp = (const f32x4*)(g + c);
    const f32x4* bp = (const f32x4*)(be + c);
    f32x4 g0 = gp[0], g1 = gp[1], e0 = bp[0], e1 = bp[1];
    s16x8 pk;
#pragma unroll
    for (int e = 0; e < 4; ++e) pk[e] = (short)f2b((x[e] - mu) * rs * g0[e] + e0[e]);
#pragma unroll
    for (int e = 0; e < 4; ++e) pk[4 + e] = (short)f2b((x[4 + e] - mu) * rs * g1[e] + e1[e]);
    *(s16x8*)(xb + (size_t)row * DM_ + c) = pk;
}

// ---------------- fused LN2 (layer 1) + final LN + Wout dot ---------------------------
__global__ __launch_bounds__(256)
void k_ln2f(const u16* __restrict__ in, const float* __restrict__ g2,
            const float* __restrict__ b2_, const float* __restrict__ gf,
            const float* __restrict__ bf_, const float* __restrict__ wout,
            const float* __restrict__ bout, float* __restrict__ out) {
    int row = blockIdx.x * 4 + (threadIdx.x >> 6);
    int l = threadIdx.x & 63;
    s16x8 raw = *(const s16x8*)(in + (size_t)row * DM_ + l * 8);
    float x[8];
#pragma unroll
    for (int e = 0; e < 8; ++e) x[e] = b2f((u16)raw[e]);
    float sum = 0.f;
#pragma unroll
    for (int e = 0; e < 8; ++e) sum += x[e];
#pragma unroll
    for (int off = 32; off > 0; off >>= 1) sum += __shfl_xor(sum, off);
    float mu = sum * (1.f / DM_);
    float sq = 0.f;
#pragma unroll
    for (int e = 0; e < 8; ++e) { float d = x[e] - mu; sq += d * d; }
#pragma unroll
    for (int off = 32; off > 0; off >>= 1) sq += __shfl_xor(sq, off);
    float rs = rsqrtf(sq * (1.f / DM_) + 1e-5f);
    int c = l * 8;
    float t[8];
#pragma unroll
    for (int e = 0; e < 8; ++e) t[e] = (x[e] - mu) * rs * g2[c + e] + b2_[c + e];
    // second LN over t
    float sum2 = 0.f;
#pragma unroll
    for (int e = 0; e < 8; ++e) sum2 += t[e];
#pragma unroll
    for (int off = 32; off > 0; off >>= 1) sum2 += __shfl_xor(sum2, off);
    float mu2 = sum2 * (1.f / DM_);
    float sq2 = 0.f;
#pragma unroll
    for (int e = 0; e < 8; ++e) { float d = t[e] - mu2; sq2 += d * d; }
#pragma unroll
    for (int off = 32; off > 0; off >>= 1) sq2 += __shfl_xor(sq2, off);
    float rs2 = rsqrtf(sq2 * (1.f / DM_) + 1e-5f);
    float p = 0.f;
#pragma unroll
    for (int e = 0; e < 8; ++e)
        p += ((t[e] - mu2) * rs2 * gf[c + e] + bf_[c + e]) * wout[c + e];
#pragma unroll
    for (int off = 32; off > 0; off >>= 1) p += __shfl_xor(p, off);
    if (l == 0) out[row] = p + bout[0];
}

// =======================================================================================
extern "C" void kernel_launch(void* const* d_in, const int* in_sizes, int n_in,
                              void* d_out, int out_size, void* d_ws, size_t ws_size,
                              hipStream_t stream) {
    const float* emb   = (const float*)d_in[0];
    const float* W0    = (const float*)d_in[1];
    const float* b0    = (const float*)d_in[2];
    const float* Wq    = (const float*)d_in[3];
    const float* bq    = (const float*)d_in[4];
    const float* Wk    = (const float*)d_in[5];
    const float* bk    = (const float*)d_in[6];
    const float* Wv    = (const float*)d_in[7];
    const float* bv    = (const float*)d_in[8];
    const float* Wo    = (const float*)d_in[9];
    const float* bo    = (const float*)d_in[10];
    const float* ln1s  = (const float*)d_in[11];
    const float* ln1b  = (const float*)d_in[12];
    const float* W1    = (const float*)d_in[13];
    const float* b1    = (const float*)d_in[14];
    const float* W2    = (const float*)d_in[15];
    const float* b2    = (const float*)d_in[16];
    const float* ln2s  = (const float*)d_in[17];
    const float* ln2b  = (const float*)d_in[18];
    const float* lnfs  = (const float*)d_in[19];
    const float* lnfb  = (const float*)d_in[20];
    const float* Wout  = (const float*)d_in[21];
    const float* bout  = (const float*)d_in[22];
    float* out = (float*)d_out;

    char* ws = (char*)d_ws;
    size_t off = 0;
    auto alloc = [&](size_t bytes) -> void* {
        void* p = ws + off;
        off += (bytes + 255) & ~(size_t)255;
        return p;
    };
    u16* xb   = (u16*)alloc((size_t)BS_ * DM_ * 2);    // 32MB  x (bf16 stream)
    u16* qb   = (u16*)alloc((size_t)BS_ * DM_ * 2);    // 32MB  (rb aliases qb)
    u16* kb   = (u16*)alloc((size_t)BS_ * DM_ * 2);    // 32MB  (h1b = kb..vb 64MB)
    u16* vb   = (u16*)alloc((size_t)BS_ * DM_ * 2);    // 32MB  (ab aliases vb)
    float* kvp   = (float*)alloc((size_t)4 * 64 * 4096 * 4);
    float* ksump = (float*)alloc((size_t)4 * 64 * 64 * 4);
    u16* wp   = (u16*)alloc((size_t)4505600 * 2);      // weight pool ~9MB

    u16* rb  = qb;     // residual r (written after qb dead)
    u16* ab  = vb;     // attn output (written after vb consumed)
    u16* h1b = kb;     // 64MB FF hidden = kb+vb regions (written after both dead)

    u16* W0t  = wp;                          // [512][608]
    u16* Wqkv = wp + 311296;                 // per layer [1536][512]
    u16* Wot  = Wqkv + 2 * 786432;           // per layer [512][512]
    u16* W1t  = Wot + 2 * 262144;            // per layer [1024][512]
    u16* W2t  = W1t + 2 * 524288;            // per layer [512][1024]

    dim3 tb(32, 8);
    k_tr<<<dim3(19, 16), tb, 0, stream>>>(W0, W0t, FIN_, DM_, FINP_);
    for (int l = 0; l < 2; ++l) {
        u16* qkvb = Wqkv + (size_t)l * 786432;
        k_tr<<<dim3(16, 16), tb, 0, stream>>>(Wq + (size_t)l * 262144, qkvb, 512, 512, 512);
        k_tr<<<dim3(16, 16), tb, 0, stream>>>(Wk + (size_t)l * 262144, qkvb + 262144, 512, 512, 512);
        k_tr<<<dim3(16, 16), tb, 0, stream>>>(Wv + (size_t)l * 262144, qkvb + 524288, 512, 512, 512);
        k_tr<<<dim3(16, 16), tb, 0, stream>>>(Wo + (size_t)l * 262144, Wot + (size_t)l * 262144, 512, 512, 512);
        k_tr<<<dim3(16, 32), tb, 0, stream>>>(W1 + (size_t)l * 524288, W1t + (size_t)l * 524288, 512, 1024, 512);
        k_tr<<<dim3(32, 16), tb, 0, stream>>>(W2 + (size_t)l * 524288, W2t + (size_t)l * 524288, 1024, 512, 1024);
    }

    // x = emb @ W0 + b0   (fp32 A staged+converted in-kernel)
    k_gemm_ef<<<1024, 256, 0, stream>>>(emb, W0t, b0, xb, 4);

    for (int l = 0; l < 2; ++l) {
        // fused QKV: N=1536, feat(elu+1) on q,k
        k_gemm<1><<<3072, 256, 0, stream>>>(xb, Wqkv + (size_t)l * 786432,
                                            bq + l * 512, bk + l * 512, bv + l * 512,
                                            nullptr, qb, kb, vb, BS_, 1536, 512, 12);
        k_kv<<<dim3(64, 4), 256, 0, stream>>>(kb, vb, kvp, ksump);
        k_attn<<<dim3(64, 64), 256, 0, stream>>>(qb, kvp, ksump, ab);
        // r = x + a@Wo + bo
        k_gemm<2><<<1024, 256, 0, stream>>>(ab, Wot + (size_t)l * 262144,
                                            bo + l * 512, nullptr, nullptr,
                                            xb, rb, nullptr, nullptr, BS_, 512, 512, 4);
        k_ln<<<8192, 256, 0, stream>>>(rb, ln1s + l * 512, ln1b + l * 512, xb);
        // h = relu(x@W1+b1)
        k_gemm<3><<<2048, 256, 0, stream>>>(xb, W1t + (size_t)l * 524288,
                                            b1 + l * 1024, nullptr, nullptr,
                                            nullptr, h1b, nullptr, nullptr, BS_, 1024, 512, 8);
        // r = x + h@W2 + b2
        k_gemm<2><<<1024, 256, 0, stream>>>(h1b, W2t + (size_t)l * 524288,
                                            b2 + l * 512, nullptr, nullptr,
                                            xb, rb, nullptr, nullptr, BS_, 512, 1024, 4);
        if (l == 0)
            k_ln<<<8192, 256, 0, stream>>>(rb, ln2s, ln2b, xb);
        else
            k_ln2f<<<8192, 256, 0, stream>>>(rb, ln2s + 512, ln2b + 512,
                                             lnfs, lnfb, Wout, bout, out);
    }
}

// Round 3
// 805.347 us; speedup vs baseline: 1.3817x; 1.0302x over previous
//
#include <hip/hip_runtime.h>
#include <math.h>

typedef unsigned short u16;
typedef short s16x8 __attribute__((ext_vector_type(8)));
typedef float f32x4 __attribute__((ext_vector_type(4)));

#define BS_   32768      // B*S
#define SEQ_  4096
#define DM_   512
#define FF_   1024
#define FIN_  586
#define FINP_ 608
#define PADC  136        // epilogue LDS stride (u16): 272B rows -> 16B aligned

__device__ __forceinline__ u16 f2b(float f) {
    union { float f; unsigned u; } a; a.f = f;
    unsigned u = a.u;
    unsigned r = (u + 0x7FFFu + ((u >> 16) & 1u)) >> 16;   // RNE
    return (u16)r;
}
__device__ __forceinline__ float b2f(u16 h) {
    union { unsigned u; float f; } a; a.u = ((unsigned)h) << 16;
    return a.f;
}

typedef __attribute__((address_space(1))) const unsigned gu32;
typedef __attribute__((address_space(3))) unsigned lu32;
__device__ __forceinline__ void glds16(const void* g, void* l) {
    __builtin_amdgcn_global_load_lds((gu32*)g, (lu32*)l, 16, 0, 0);
}

// ---------------- batched weight transpose + bf16 convert (one launch) ----------------
__device__ __forceinline__ void tr_tile(const float* __restrict__ W, u16* __restrict__ Wt,
                                        int K, int N, int Kpad, int tidx, int ktiles,
                                        float (*t)[33]) {
    int kb = (tidx % ktiles) << 5, nb = (tidx / ktiles) << 5;
    int tx = threadIdx.x, ty = threadIdx.y;          // 32 x 8
#pragma unroll
    for (int j = 0; j < 32; j += 8) {
        int k = kb + ty + j;
        t[ty + j][tx] = (k < K) ? W[(size_t)k * N + nb + tx] : 0.f;
    }
    __syncthreads();
#pragma unroll
    for (int j = 0; j < 32; j += 8) {
        Wt[(size_t)(nb + ty + j) * Kpad + kb + tx] = f2b(t[tx][ty + j]);
    }
}

__global__ void k_tr_all(const float* __restrict__ W0, const float* __restrict__ Wq,
                         const float* __restrict__ Wk, const float* __restrict__ Wv,
                         const float* __restrict__ Wo, const float* __restrict__ W1,
                         const float* __restrict__ W2,
                         u16* __restrict__ W0t, u16* __restrict__ Wqkv,
                         u16* __restrict__ Wot, u16* __restrict__ W1t,
                         u16* __restrict__ W2t) {
    __shared__ float t[32][33];
    int b = blockIdx.x;
    if (b < 304) { tr_tile(W0, W0t, FIN_, DM_, FINP_, b, 19, t); return; }
    b -= 304;
    int l = b >> 11;              // 2048 tiles per layer
    int r = b & 2047;
    if (r < 768) {                // q,k,v : 256 tiles each
        int sel = r >> 8, ti = r & 255;
        const float* src = sel == 0 ? Wq : (sel == 1 ? Wk : Wv);
        tr_tile(src + (size_t)l * 262144, Wqkv + (size_t)l * 786432 + (size_t)sel * 262144,
                512, 512, 512, ti, 16, t);
    } else if (r < 1024) {
        tr_tile(Wo + (size_t)l * 262144, Wot + (size_t)l * 262144, 512, 512, 512, r - 768, 16, t);
    } else if (r < 1536) {
        tr_tile(W1 + (size_t)l * 524288, W1t + (size_t)l * 524288, 512, 1024, 512, r - 1024, 16, t);
    } else {
        tr_tile(W2 + (size_t)l * 524288, W2t + (size_t)l * 524288, 1024, 512, 1024, r - 1536, 32, t);
    }
}

// ---------------- MFMA GEMM (m97 structure + coalesced LDS-bounce epilogue) -----------
// 128x128 tile, BK=32, global_load_lds 16B staging, XCD-swizzled 1-D grid.
// EPI: 1 = QKV split (feat on q,k), 2 = residual-add (bf16 resid), 3 = relu
template<int EPI>
__global__ __launch_bounds__(256)
void k_gemm(const u16* __restrict__ A, const u16* __restrict__ Bt,
            const float* __restrict__ bias0, const float* __restrict__ bias1,
            const float* __restrict__ bias2,
            const u16* __restrict__ resid,
            u16* __restrict__ out0, u16* __restrict__ out1, u16* __restrict__ out2,
            int M, int N, int K, int NT) {
    __shared__ __align__(16) u16 sA[128 * 32];
    __shared__ __align__(16) u16 sB[128 * 32];
    __shared__ __align__(16) u16 sC[128 * PADC];
    const int nwg = gridDim.x;
    const int cpx = nwg >> 3;                       // nwg % 8 == 0 for all our launches
    const int wg = (blockIdx.x & 7) * cpx + (blockIdx.x >> 3);   // XCD-contiguous chunks
    const int mt = wg / NT, nt = wg - mt * NT;      // n-tile fastest -> A shared on-XCD
    const int m0 = mt << 7, n0 = nt << 7;
    const int tid = threadIdx.x;
    const int w = tid >> 6, l = tid & 63;
    const int wm = (w >> 1) << 6, wn = (w & 1) << 6;
    const int lr = l & 15, lg = l >> 4;
    const int srow = tid >> 2, sc8 = (tid & 3) << 3;

    f32x4 acc[4][4] = {};
    const u16* Ap = A + (size_t)(m0 + srow) * K + sc8;
    const u16* Bp = Bt + (size_t)(n0 + srow) * K + sc8;
    u16* sAp = sA + tid * 8;                        // lane-linear: byte off = tid*16
    u16* sBp = sB + tid * 8;

    for (int k0 = 0; k0 < K; k0 += 32) {
        glds16(Ap + k0, sAp);
        glds16(Ap + (size_t)64 * K + k0, sAp + 2048);
        glds16(Bp + k0, sBp);
        glds16(Bp + (size_t)64 * K + k0, sBp + 2048);
        __syncthreads();
        s16x8 af[4], bfr[4];
#pragma unroll
        for (int i = 0; i < 4; ++i) af[i] = *(const s16x8*)(sA + (wm + i * 16 + lr) * 32 + (lg << 3));
#pragma unroll
        for (int j = 0; j < 4; ++j) bfr[j] = *(const s16x8*)(sB + (wn + j * 16 + lr) * 32 + (lg << 3));
#pragma unroll
        for (int i = 0; i < 4; ++i)
#pragma unroll
            for (int j = 0; j < 4; ++j)
                acc[i][j] = __builtin_amdgcn_mfma_f32_16x16x32_bf16(af[i], bfr[j], acc[i][j], 0, 0, 0);
        __syncthreads();
    }

    // --- epilogue stage 1: frags (+bias, fp32) -> bf16 -> sC ---------------------------
    // D map (verified): row = wm+i*16+lg*4+r, col = wn+j*16+lr
    const int seg = (EPI == 1) ? (n0 >> 9) : 0;     // 0=q 1=k 2=v when N=1536
    const float* bias = (EPI == 1) ? (seg == 0 ? bias0 : (seg == 1 ? bias1 : bias2)) : bias0;
    u16* dst = (EPI == 1) ? (seg == 0 ? out0 : (seg == 1 ? out1 : out2)) : out0;
    const int ldo = (EPI == 1) ? 512 : N;
    const int ncol0 = (EPI == 1) ? (n0 & 511) : n0;
#pragma unroll
    for (int j = 0; j < 4; ++j) {
        const int col = wn + j * 16 + lr;
        const float bv = bias[ncol0 + col];
#pragma unroll
        for (int i = 0; i < 4; ++i) {
#pragma unroll
            for (int r = 0; r < 4; ++r) {
                const int row = wm + i * 16 + (lg << 2) + r;
                sC[row * PADC + col] = f2b(acc[i][j][r] + bv);
            }
        }
    }
    __syncthreads();

    // --- epilogue stage 2: coalesced 16B stores (+feat/relu/resid) ---------------------
#pragma unroll
    for (int t = 0; t < 8; ++t) {
        const int idx = t * 256 + tid;              // 0..2047
        const int row = idx >> 4;
        const int c8 = (idx & 15) << 3;
        s16x8 v8 = *(const s16x8*)(sC + row * PADC + c8);
        size_t gaddr = (size_t)(m0 + row) * ldo + ncol0 + c8;
        s16x8 o;
        if constexpr (EPI == 1) {
            if (seg < 2) {
#pragma unroll
                for (int e = 0; e < 8; ++e) {
                    float v = b2f((u16)v8[e]);
                    v = (v > 0.f) ? v + 1.f : __expf(v);   // elu+1
                    o[e] = (short)f2b(v);
                }
            } else o = v8;
        } else if constexpr (EPI == 2) {
            s16x8 rv = *(const s16x8*)(resid + gaddr);
#pragma unroll
            for (int e = 0; e < 8; ++e)
                o[e] = (short)f2b(b2f((u16)v8[e]) + b2f((u16)rv[e]));
        } else {
#pragma unroll
            for (int e = 0; e < 8; ++e) {
                float v = b2f((u16)v8[e]);
                o[e] = (short)f2b(fmaxf(v, 0.f));
            }
        }
        *(s16x8*)(dst + gaddr) = o;
    }
}

// ---------------- emb GEMM: A fp32 [32768][586] (pad->608), converts while staging ----
__global__ __launch_bounds__(256)
void k_gemm_ef(const float* __restrict__ A, const u16* __restrict__ Bt,
               const float* __restrict__ bias, u16* __restrict__ out, int NT) {
    __shared__ __align__(16) u16 sA[128 * 32];
    __shared__ __align__(16) u16 sB[128 * 32];
    __shared__ __align__(16) u16 sC[128 * PADC];
    const int nwg = gridDim.x;
    const int cpx = nwg >> 3;
    const int wg = (blockIdx.x & 7) * cpx + (blockIdx.x >> 3);
    const int mt = wg / NT, nt = wg - mt * NT;
    const int m0 = mt << 7, n0 = nt << 7;
    const int tid = threadIdx.x;
    const int w = tid >> 6, l = tid & 63;
    const int wm = (w >> 1) << 6, wn = (w & 1) << 6;
    const int lr = l & 15, lg = l >> 4;
    const int srow = tid >> 2, sc8 = (tid & 3) << 3;

    f32x4 acc[4][4] = {};
    const u16* Bp = Bt + (size_t)(n0 + srow) * FINP_ + sc8;
    u16* sBp = sB + tid * 8;

    for (int k0 = 0; k0 < FINP_; k0 += 32) {
        const int gc = k0 + sc8;
        float av0[8], av1[8];
        const float* a0p = A + (size_t)(m0 + srow) * FIN_ + gc;
        const float* a1p = A + (size_t)(m0 + 64 + srow) * FIN_ + gc;
        if (gc + 7 < FIN_) {
#pragma unroll
            for (int e = 0; e < 8; e += 4) {
                f32x4 t0 = *(const f32x4*)(a0p + e);
                f32x4 t1 = *(const f32x4*)(a1p + e);
#pragma unroll
                for (int q = 0; q < 4; ++q) { av0[e + q] = t0[q]; av1[e + q] = t1[q]; }
            }
        } else {
#pragma unroll
            for (int e = 0; e < 8; ++e) {
                bool ok = (gc + e) < FIN_;
                av0[e] = ok ? a0p[e] : 0.f;
                av1[e] = ok ? a1p[e] : 0.f;
            }
        }
        s16x8 p0, p1;
#pragma unroll
        for (int e = 0; e < 8; ++e) { p0[e] = (short)f2b(av0[e]); p1[e] = (short)f2b(av1[e]); }
        *(s16x8*)(sA + srow * 32 + sc8) = p0;
        *(s16x8*)(sA + (srow + 64) * 32 + sc8) = p1;
        glds16(Bp + k0, sBp);
        glds16(Bp + (size_t)64 * FINP_ + k0, sBp + 2048);
        __syncthreads();
        s16x8 af[4], bfr[4];
#pragma unroll
        for (int i = 0; i < 4; ++i) af[i] = *(const s16x8*)(sA + (wm + i * 16 + lr) * 32 + (lg << 3));
#pragma unroll
        for (int j = 0; j < 4; ++j) bfr[j] = *(const s16x8*)(sB + (wn + j * 16 + lr) * 32 + (lg << 3));
#pragma unroll
        for (int i = 0; i < 4; ++i)
#pragma unroll
            for (int j = 0; j < 4; ++j)
                acc[i][j] = __builtin_amdgcn_mfma_f32_16x16x32_bf16(af[i], bfr[j], acc[i][j], 0, 0, 0);
        __syncthreads();
    }
#pragma unroll
    for (int j = 0; j < 4; ++j) {
        const int col = wn + j * 16 + lr;
        const float bv = bias[n0 + col];
#pragma unroll
        for (int i = 0; i < 4; ++i)
#pragma unroll
            for (int r = 0; r < 4; ++r) {
                const int row = wm + i * 16 + (lg << 2) + r;
                sC[row * PADC + col] = f2b(acc[i][j][r] + bv);
            }
    }
    __syncthreads();
#pragma unroll
    for (int t = 0; t < 8; ++t) {
        const int idx = t * 256 + tid;
        const int row = idx >> 4;
        const int c8 = (idx & 15) << 3;
        s16x8 v8 = *(const s16x8*)(sC + row * PADC + c8);
        *(s16x8*)(out + (size_t)(m0 + row) * DM_ + n0 + c8) = v8;
    }
}

// ---------------- kv einsum: kv[b,h,d,m] = sum_s k*v ; ksum[b,h,d] = sum_s k ----------
__global__ __launch_bounds__(256)
void k_kv(const u16* __restrict__ kb_, const u16* __restrict__ vb_,
          float* __restrict__ kvp, float* __restrict__ ksump) {
    __shared__ float sk[64 * 68], sv[64 * 68];
    int bh = blockIdx.x, b = bh >> 3, h = bh & 7;
    int ch = blockIdx.y;
    int tid = threadIdx.x;
    int d0 = (tid & 15) << 2, m0 = (tid >> 4) << 2;
    float acc[4][4] = {};
    float ks[4] = {0.f, 0.f, 0.f, 0.f};
    size_t gbase = ((size_t)b * SEQ_ + (size_t)ch * 1024) * DM_ + h * 64;

    for (int st = 0; st < 1024; st += 64) {
#pragma unroll
        for (int i = 0; i < 2; ++i) {
            int li = tid + (i << 8);
            int r = li >> 3, c8 = (li & 7) << 3;
            s16x8 kv_ = *(const s16x8*)(kb_ + gbase + (size_t)(st + r) * DM_ + c8);
            s16x8 vv_ = *(const s16x8*)(vb_ + gbase + (size_t)(st + r) * DM_ + c8);
#pragma unroll
            for (int e = 0; e < 8; ++e) {
                sk[r * 68 + c8 + e] = b2f((u16)kv_[e]);
                sv[r * 68 + c8 + e] = b2f((u16)vv_[e]);
            }
        }
        __syncthreads();
        for (int s = 0; s < 64; ++s) {
            f32x4 kd = *(const f32x4*)(sk + s * 68 + d0);
            f32x4 vm = *(const f32x4*)(sv + s * 68 + m0);
#pragma unroll
            for (int i = 0; i < 4; ++i)
#pragma unroll
                for (int j = 0; j < 4; ++j) acc[i][j] += kd[i] * vm[j];
            if ((tid >> 4) == 0) { ks[0] += kd[0]; ks[1] += kd[1]; ks[2] += kd[2]; ks[3] += kd[3]; }
        }
        __syncthreads();
    }
    float* kvo = kvp + ((size_t)ch * 64 + bh) * 4096;
#pragma unroll
    for (int i = 0; i < 4; ++i)
#pragma unroll
        for (int j = 0; j < 4; ++j) kvo[(d0 + i) * 64 + m0 + j] = acc[i][j];
    if ((tid >> 4) == 0) {
        float* kso = ksump + ((size_t)ch * 64 + bh) * 64;
#pragma unroll
        for (int e = 0; e < 4; ++e) kso[d0 + e] = ks[e];
    }
}

// ---------------- attention apply: a = (q . kv) / (q . ksum + eps) --------------------
__global__ __launch_bounds__(256)
void k_attn(const u16* __restrict__ qb_, const float* __restrict__ kvp,
            const float* __restrict__ ksump, u16* __restrict__ ab_) {
    __shared__ float skv[64 * 64];
    __shared__ float sq[64 * 65];
    __shared__ float sks[64];
    int tid = threadIdx.x;
    int bh = blockIdx.y, b = bh >> 3, h = bh & 7;
    int s0 = blockIdx.x << 6;

    for (int i = tid; i < 4096; i += 256) {
        float v = 0.f;
#pragma unroll
        for (int c = 0; c < 4; ++c) v += kvp[((size_t)c * 64 + bh) * 4096 + i];
        skv[i] = v;
    }
    if (tid < 64) {
        float v = 0.f;
#pragma unroll
        for (int c = 0; c < 4; ++c) v += ksump[((size_t)c * 64 + bh) * 64 + tid];
        sks[tid] = v;
    }
#pragma unroll
    for (int i = 0; i < 2; ++i) {
        int li = tid + (i << 8);
        int r = li >> 3, c8 = (li & 7) << 3;
        s16x8 v = *(const s16x8*)(qb_ + ((size_t)b * SEQ_ + s0 + r) * DM_ + h * 64 + c8);
#pragma unroll
        for (int e = 0; e < 8; ++e) sq[r * 65 + c8 + e] = b2f((u16)v[e]);
    }
    __syncthreads();

    int sl = tid >> 2, m0 = (tid & 3) << 4;
    float den = 0.f;
    for (int d = 0; d < 64; ++d) den += sq[sl * 65 + d] * sks[d];
    float z = 1.f / (den + 1e-6f);

    float acc[16] = {};
    for (int d = 0; d < 64; ++d) {
        float qv = sq[sl * 65 + d];
        const f32x4* kp = (const f32x4*)(skv + d * 64 + m0);
#pragma unroll
        for (int j4 = 0; j4 < 4; ++j4) {
            f32x4 kv4 = kp[j4];
#pragma unroll
            for (int e = 0; e < 4; ++e) acc[j4 * 4 + e] += qv * kv4[e];
        }
    }
    u16* op = ab_ + ((size_t)b * SEQ_ + s0 + sl) * DM_ + h * 64 + m0;
    s16x8 o0, o1;
#pragma unroll
    for (int e = 0; e < 8; ++e) o0[e] = (short)f2b(acc[e] * z);
#pragma unroll
    for (int e = 0; e < 8; ++e) o1[e] = (short)f2b(acc[8 + e] * z);
    *(s16x8*)op = o0;
    *(s16x8*)(op + 8) = o1;
}

// ---------------- LayerNorm over 512 (bf16 in -> bf16 out) ----------------------------
__global__ __launch_bounds__(256)
void k_ln(const u16* __restrict__ in, const float* __restrict__ g,
          const float* __restrict__ be, u16* __restrict__ xb) {
    int row = blockIdx.x * 4 + (threadIdx.x >> 6);
    int l = threadIdx.x & 63;
    s16x8 raw = *(const s16x8*)(in + (size_t)row * DM_ + l * 8);
    float x[8];
#pragma unroll
    for (int e = 0; e < 8; ++e) x[e] = b2f((u16)raw[e]);
    float sum = 0.f;
#pragma unroll
    for (int e = 0; e < 8; ++e) sum += x[e];
#pragma unroll
    for (int off = 32; off > 0; off >>= 1) sum += __shfl_xor(sum, off);
    float mu = sum * (1.f / DM_);
    float sq = 0.f;
#pragma unroll
    for (int e = 0; e < 8; ++e) { float d = x[e] - mu; sq += d * d; }
#pragma unroll
    for (int off = 32; off > 0; off >>= 1) sq += __shfl_xor(sq, off);
    float rs = rsqrtf(sq * (1.f / DM_) + 1e-5f);
    int c = l * 8;
    const f32x4* gp = (const f32x4*)(g + c);
    const f32x4* bp = (const f32x4*)(be + c);
    f32x4 g0 = gp[0], g1 = gp[1], e0 = bp[0], e1 = bp[1];
    s16x8 pk;
#pragma unroll
    for (int e = 0; e < 4; ++e) pk[e] = (short)f2b((x[e] - mu) * rs * g0[e] + e0[e]);
#pragma unroll
    for (int e = 0; e < 4; ++e) pk[4 + e] = (short)f2b((x[4 + e] - mu) * rs * g1[e] + e1[e]);
    *(s16x8*)(xb + (size_t)row * DM_ + c) = pk;
}

// ---------------- fused LN2 (layer 1) + final LN + Wout dot ---------------------------
__global__ __launch_bounds__(256)
void k_ln2f(const u16* __restrict__ in, const float* __restrict__ g2,
            const float* __restrict__ b2_, const float* __restrict__ gf,
            const float* __restrict__ bf_, const float* __restrict__ wout,
            const float* __restrict__ bout, float* __restrict__ out) {
    int row = blockIdx.x * 4 + (threadIdx.x >> 6);
    int l = threadIdx.x & 63;
    s16x8 raw = *(const s16x8*)(in + (size_t)row * DM_ + l * 8);
    float x[8];
#pragma unroll
    for (int e = 0; e < 8; ++e) x[e] = b2f((u16)raw[e]);
    float sum = 0.f;
#pragma unroll
    for (int e = 0; e < 8; ++e) sum += x[e];
#pragma unroll
    for (int off = 32; off > 0; off >>= 1) sum += __shfl_xor(sum, off);
    float mu = sum * (1.f / DM_);
    float sq = 0.f;
#pragma unroll
    for (int e = 0; e < 8; ++e) { float d = x[e] - mu; sq += d * d; }
#pragma unroll
    for (int off = 32; off > 0; off >>= 1) sq += __shfl_xor(sq, off);
    float rs = rsqrtf(sq * (1.f / DM_) + 1e-5f);
    int c = l * 8;
    float t[8];
#pragma unroll
    for (int e = 0; e < 8; ++e) t[e] = (x[e] - mu) * rs * g2[c + e] + b2_[c + e];
    float sum2 = 0.f;
#pragma unroll
    for (int e = 0; e < 8; ++e) sum2 += t[e];
#pragma unroll
    for (int off = 32; off > 0; off >>= 1) sum2 += __shfl_xor(sum2, off);
    float mu2 = sum2 * (1.f / DM_);
    float sq2 = 0.f;
#pragma unroll
    for (int e = 0; e < 8; ++e) { float d = t[e] - mu2; sq2 += d * d; }
#pragma unroll
    for (int off = 32; off > 0; off >>= 1) sq2 += __shfl_xor(sq2, off);
    float rs2 = rsqrtf(sq2 * (1.f / DM_) + 1e-5f);
    float p = 0.f;
#pragma unroll
    for (int e = 0; e < 8; ++e)
        p += ((t[e] - mu2) * rs2 * gf[c + e] + bf_[c + e]) * wout[c + e];
#pragma unroll
    for (int off = 32; off > 0; off >>= 1) p += __shfl_xor(p, off);
    if (l == 0) out[row] = p + bout[0];
}

// =======================================================================================
extern "C" void kernel_launch(void* const* d_in, const int* in_sizes, int n_in,
                              void* d_out, int out_size, void* d_ws, size_t ws_size,
                              hipStream_t stream) {
    const float* emb   = (const float*)d_in[0];
    const float* W0    = (const float*)d_in[1];
    const float* b0    = (const float*)d_in[2];
    const float* Wq    = (const float*)d_in[3];
    const float* bq    = (const float*)d_in[4];
    const float* Wk    = (const float*)d_in[5];
    const float* bk    = (const float*)d_in[6];
    const float* Wv    = (const float*)d_in[7];
    const float* bv    = (const float*)d_in[8];
    const float* Wo    = (const float*)d_in[9];
    const float* bo    = (const float*)d_in[10];
    const float* ln1s  = (const float*)d_in[11];
    const float* ln1b  = (const float*)d_in[12];
    const float* W1    = (const float*)d_in[13];
    const float* b1    = (const float*)d_in[14];
    const float* W2    = (const float*)d_in[15];
    const float* b2    = (const float*)d_in[16];
    const float* ln2s  = (const float*)d_in[17];
    const float* ln2b  = (const float*)d_in[18];
    const float* lnfs  = (const float*)d_in[19];
    const float* lnfb  = (const float*)d_in[20];
    const float* Wout  = (const float*)d_in[21];
    const float* bout  = (const float*)d_in[22];
    float* out = (float*)d_out;

    char* ws = (char*)d_ws;
    size_t off = 0;
    auto alloc = [&](size_t bytes) -> void* {
        void* p = ws + off;
        off += (bytes + 255) & ~(size_t)255;
        return p;
    };
    u16* xb   = (u16*)alloc((size_t)BS_ * DM_ * 2);    // 32MB  x (bf16 stream)
    u16* qb   = (u16*)alloc((size_t)BS_ * DM_ * 2);    // 32MB  (rb aliases qb)
    u16* kb   = (u16*)alloc((size_t)BS_ * DM_ * 2);    // 32MB  (h1b = kb..vb 64MB)
    u16* vb   = (u16*)alloc((size_t)BS_ * DM_ * 2);    // 32MB  (ab aliases vb)
    float* kvp   = (float*)alloc((size_t)4 * 64 * 4096 * 4);
    float* ksump = (float*)alloc((size_t)4 * 64 * 64 * 4);
    u16* wp   = (u16*)alloc((size_t)4505600 * 2);      // weight pool ~9MB

    u16* rb  = qb;     // residual r (written after qb dead)
    u16* ab  = vb;     // attn output (written after vb consumed)
    u16* h1b = kb;     // 64MB FF hidden = kb+vb regions (written after both dead)

    u16* W0t  = wp;                          // [512][608]
    u16* Wqkv = wp + 311296;                 // per layer [1536][512]
    u16* Wot  = Wqkv + 2 * 786432;           // per layer [512][512]
    u16* W1t  = Wot + 2 * 262144;            // per layer [1024][512]
    u16* W2t  = W1t + 2 * 524288;            // per layer [512][1024]

    k_tr_all<<<4400, dim3(32, 8), 0, stream>>>(W0, Wq, Wk, Wv, Wo, W1, W2,
                                               W0t, Wqkv, Wot, W1t, W2t);

    // x = emb @ W0 + b0   (fp32 A staged+converted in-kernel)
    k_gemm_ef<<<1024, 256, 0, stream>>>(emb, W0t, b0, xb, 4);

    for (int l = 0; l < 2; ++l) {
        // fused QKV: N=1536, feat(elu+1) on q,k
        k_gemm<1><<<3072, 256, 0, stream>>>(xb, Wqkv + (size_t)l * 786432,
                                            bq + l * 512, bk + l * 512, bv + l * 512,
                                            nullptr, qb, kb, vb, BS_, 1536, 512, 12);
        k_kv<<<dim3(64, 4), 256, 0, stream>>>(kb, vb, kvp, ksump);
        k_attn<<<dim3(64, 64), 256, 0, stream>>>(qb, kvp, ksump, ab);
        // r = x + a@Wo + bo
        k_gemm<2><<<1024, 256, 0, stream>>>(ab, Wot + (size_t)l * 262144,
                                            bo + l * 512, nullptr, nullptr,
                                            xb, rb, nullptr, nullptr, BS_, 512, 512, 4);
        k_ln<<<8192, 256, 0, stream>>>(rb, ln1s + l * 512, ln1b + l * 512, xb);
        // h = relu(x@W1+b1)
        k_gemm<3><<<2048, 256, 0, stream>>>(xb, W1t + (size_t)l * 524288,
                                            b1 + l * 1024, nullptr, nullptr,
                                            nullptr, h1b, nullptr, nullptr, BS_, 1024, 512, 8);
        // r = x + h@W2 + b2
        k_gemm<2><<<1024, 256, 0, stream>>>(h1b, W2t + (size_t)l * 524288,
                                            b2 + l * 512, nullptr, nullptr,
                                            xb, rb, nullptr, nullptr, BS_, 512, 1024, 4);
        if (l == 0)
            k_ln<<<8192, 256, 0, stream>>>(rb, ln2s, ln2b, xb);
        else
            k_ln2f<<<8192, 256, 0, stream>>>(rb, ln2s + 512, ln2b + 512,
                                             lnfs, lnfb, Wout, bout, out);
    }
}

// Round 4
// 798.522 us; speedup vs baseline: 1.3935x; 1.0085x over previous
//
#include <hip/hip_runtime.h>
#include <hip/hip_bf16.h>
#include <math.h>

typedef unsigned short u16;
typedef short s16x8 __attribute__((ext_vector_type(8)));
typedef float f32x4 __attribute__((ext_vector_type(4)));

#define BS_   32768      // B*S
#define SEQ_  4096
#define DM_   512
#define FF_   1024
#define FIN_  586
#define FINP_ 640        // emb K padded to multiple of 64
#define PADC  136        // epilogue LDS stride (u16)

__device__ __forceinline__ u16 f2b(float f) {
    __hip_bfloat16 h = __float2bfloat16(f);      // RNE, hw v_cvt on gfx950
    return *reinterpret_cast<u16*>(&h);
}
__device__ __forceinline__ float b2f(u16 h) {
    union { unsigned u; float f; } a; a.u = ((unsigned)h) << 16;
    return a.f;
}

typedef __attribute__((address_space(1))) const unsigned gu32;
typedef __attribute__((address_space(3))) unsigned lu32;
__device__ __forceinline__ void glds16(const void* g, void* l) {
    __builtin_amdgcn_global_load_lds((gu32*)g, (lu32*)l, 16, 0, 0);
}

// ---------------- batched weight transpose + bf16 convert (one launch) ----------------
__device__ __forceinline__ void tr_tile(const float* __restrict__ W, u16* __restrict__ Wt,
                                        int K, int N, int Kpad, int tidx, int ktiles,
                                        float (*t)[33]) {
    int kb = (tidx % ktiles) << 5, nb = (tidx / ktiles) << 5;
    int tx = threadIdx.x, ty = threadIdx.y;          // 32 x 8
#pragma unroll
    for (int j = 0; j < 32; j += 8) {
        int k = kb + ty + j;
        t[ty + j][tx] = (k < K) ? W[(size_t)k * N + nb + tx] : 0.f;
    }
    __syncthreads();
#pragma unroll
    for (int j = 0; j < 32; j += 8) {
        Wt[(size_t)(nb + ty + j) * Kpad + kb + tx] = f2b(t[tx][ty + j]);
    }
}

__global__ void k_tr_all(const float* __restrict__ W0, const float* __restrict__ Wq,
                         const float* __restrict__ Wk, const float* __restrict__ Wv,
                         const float* __restrict__ Wo, const float* __restrict__ W1,
                         const float* __restrict__ W2,
                         u16* __restrict__ W0t, u16* __restrict__ Wqkv,
                         u16* __restrict__ Wot, u16* __restrict__ W1t,
                         u16* __restrict__ W2t) {
    __shared__ float t[32][33];
    int b = blockIdx.x;
    if (b < 320) { tr_tile(W0, W0t, FIN_, DM_, FINP_, b, 20, t); return; }   // 20x16 tiles
    b -= 320;
    int l = b >> 11;              // 2048 tiles per layer
    int r = b & 2047;
    if (r < 768) {                // q,k,v : 256 tiles each
        int sel = r >> 8, ti = r & 255;
        const float* src = sel == 0 ? Wq : (sel == 1 ? Wk : Wv);
        tr_tile(src + (size_t)l * 262144, Wqkv + (size_t)l * 786432 + (size_t)sel * 262144,
                512, 512, 512, ti, 16, t);
    } else if (r < 1024) {
        tr_tile(Wo + (size_t)l * 262144, Wot + (size_t)l * 262144, 512, 512, 512, r - 768, 16, t);
    } else if (r < 1536) {
        tr_tile(W1 + (size_t)l * 524288, W1t + (size_t)l * 524288, 512, 1024, 512, r - 1024, 16, t);
    } else {
        tr_tile(W2 + (size_t)l * 524288, W2t + (size_t)l * 524288, 1024, 512, 1024, r - 1536, 32, t);
    }
}

// ---------------- embeddings -> bf16 padded [BS][640] ---------------------------------
__global__ __launch_bounds__(256)
void k_emb(const float* __restrict__ E, u16* __restrict__ Ep) {
    const int total8 = BS_ * (FINP_ / 8);
    for (int i = blockIdx.x * 256 + threadIdx.x; i < total8; i += gridDim.x * 256) {
        int rr = i / (FINP_ / 8), c = (i % (FINP_ / 8)) * 8;
        const float* rp = E + (size_t)rr * FIN_ + c;
        s16x8 o;
#pragma unroll
        for (int e = 0; e < 8; ++e) {
            float v = (c + e < FIN_) ? rp[e] : 0.f;
            o[e] = (short)f2b(v);
        }
        *(s16x8*)(Ep + (size_t)rr * FINP_ + c) = o;
    }
}

// ---------------- MFMA GEMM: BK=64, T2-swizzled LDS, 2-pass coalesced epilogue --------
// 128x128 tile, global_load_lds 16B staging (linear dest, swizzled SOURCE), XCD swizzle.
// EPI: 0 = bias only, 1 = QKV split (feat on q,k), 2 = residual-add, 3 = relu
template<int EPI>
__global__ __launch_bounds__(256)
void k_gemm(const u16* __restrict__ A, const u16* __restrict__ Bt,
            const float* __restrict__ bias0, const float* __restrict__ bias1,
            const float* __restrict__ bias2,
            const u16* __restrict__ resid,
            u16* __restrict__ out0, u16* __restrict__ out1, u16* __restrict__ out2,
            int M, int N, int K, int NT) {
    __shared__ __align__(16) u16 smem[16384];     // 32KB pool: sA|sB staging, sC epilogue
    u16* sA = smem;                                // [128][64]
    u16* sB = smem + 8192;                         // [128][64]
    u16* sC = smem;                                // [64][PADC] (union, used after loop)

    const int nwg = gridDim.x;
    const int cpx = nwg >> 3;                      // nwg % 8 == 0 always here
    const int wg = (blockIdx.x & 7) * cpx + (blockIdx.x >> 3);
    const int mt = wg / NT, nt = wg - mt * NT;
    const int m0 = mt << 7, n0 = nt << 7;
    const int tid = threadIdx.x;
    const int w = tid >> 6, l = tid & 63;
    const int wm = (w >> 1) << 6, wn = (w & 1) << 6;
    const int lr = l & 15, lg = l >> 4;

    // staging: 256 thr x 16B = 32 rows of 128B per call; 4 calls per operand tile
    const int srow = tid >> 3;                     // 0..31
    const int swzk = (((tid & 7) ^ (tid >> 3)) & 7) << 3;   // swizzled k-offset (elems)
    const u16* Ap = A + (size_t)(m0 + srow) * K + swzk;
    const u16* Bp = Bt + (size_t)(n0 + srow) * K + swzk;
    u16* sAp = sA + tid * 8;
    u16* sBp = sB + tid * 8;

    // read-side swizzled chunk offsets (elems): logical chunk c=ks*4+lg, row-phase lr&7
    const int rph = lr & 7;
    const int axk0 = ((0 + lg) ^ rph) << 3;
    const int axk1 = ((4 + lg) ^ rph) << 3;

    f32x4 acc[4][4] = {};

    for (int k0 = 0; k0 < K; k0 += 64) {
#pragma unroll
        for (int g = 0; g < 4; ++g) {
            glds16(Ap + (size_t)(g * 32) * K + k0, sAp + g * 2048);
            glds16(Bp + (size_t)(g * 32) * K + k0, sBp + g * 2048);
        }
        __syncthreads();
        s16x8 af[4], bfr[4];
#pragma unroll
        for (int i = 0; i < 4; ++i) af[i] = *(const s16x8*)(sA + (wm + i * 16 + lr) * 64 + axk0);
#pragma unroll
        for (int j = 0; j < 4; ++j) bfr[j] = *(const s16x8*)(sB + (wn + j * 16 + lr) * 64 + axk0);
#pragma unroll
        for (int i = 0; i < 4; ++i)
#pragma unroll
            for (int j = 0; j < 4; ++j)
                acc[i][j] = __builtin_amdgcn_mfma_f32_16x16x32_bf16(af[i], bfr[j], acc[i][j], 0, 0, 0);
#pragma unroll
        for (int i = 0; i < 4; ++i) af[i] = *(const s16x8*)(sA + (wm + i * 16 + lr) * 64 + axk1);
#pragma unroll
        for (int j = 0; j < 4; ++j) bfr[j] = *(const s16x8*)(sB + (wn + j * 16 + lr) * 64 + axk1);
#pragma unroll
        for (int i = 0; i < 4; ++i)
#pragma unroll
            for (int j = 0; j < 4; ++j)
                acc[i][j] = __builtin_amdgcn_mfma_f32_16x16x32_bf16(af[i], bfr[j], acc[i][j], 0, 0, 0);
        __syncthreads();
    }

    // ---- epilogue: 2 passes of 64 rows through sC (union with staging) ----
    const int seg = (EPI == 1) ? (n0 >> 9) : 0;     // 0=q 1=k 2=v when N=1536
    const float* bias = (EPI == 1) ? (seg == 0 ? bias0 : (seg == 1 ? bias1 : bias2)) : bias0;
    u16* dst = (EPI == 1) ? (seg == 0 ? out0 : (seg == 1 ? out1 : out2)) : out0;
    const int ldo = (EPI == 1) ? 512 : N;
    const int ncol0 = (EPI == 1) ? (n0 & 511) : n0;

#pragma unroll
    for (int pass = 0; pass < 2; ++pass) {
        if ((w >> 1) == pass) {                     // waves owning rows pass*64..+63
#pragma unroll
            for (int j = 0; j < 4; ++j) {
                const int col = wn + j * 16 + lr;
                const float bv = bias[ncol0 + col];
#pragma unroll
                for (int i = 0; i < 4; ++i)
#pragma unroll
                    for (int r = 0; r < 4; ++r) {
                        const int row = i * 16 + (lg << 2) + r;     // local 0..63
                        sC[row * PADC + col] = f2b(acc[i][j][r] + bv);
                    }
            }
        }
        __syncthreads();
        const int rbase = m0 + (pass << 6);
#pragma unroll
        for (int t = 0; t < 4; ++t) {
            const int idx = t * 256 + tid;          // 0..1023
            const int row = idx >> 4;
            const int c8 = (idx & 15) << 3;
            s16x8 v8 = *(const s16x8*)(sC + row * PADC + c8);
            size_t gaddr = (size_t)(rbase + row) * ldo + ncol0 + c8;
            s16x8 o = v8;
            if constexpr (EPI == 1) {
                if (seg < 2) {
#pragma unroll
                    for (int e = 0; e < 8; ++e) {
                        float v = b2f((u16)v8[e]);
                        v = (v > 0.f) ? v + 1.f : __expf(v);   // elu+1
                        o[e] = (short)f2b(v);
                    }
                }
            } else if constexpr (EPI == 2) {
                s16x8 rv = *(const s16x8*)(resid + gaddr);
#pragma unroll
                for (int e = 0; e < 8; ++e)
                    o[e] = (short)f2b(b2f((u16)v8[e]) + b2f((u16)rv[e]));
            } else if constexpr (EPI == 3) {
#pragma unroll
                for (int e = 0; e < 8; ++e)
                    o[e] = (short)f2b(fmaxf(b2f((u16)v8[e]), 0.f));
            }
            *(s16x8*)(dst + gaddr) = o;
        }
        __syncthreads();
    }
}

// ---------------- kv einsum: kv[b,h,d,m] = sum_s k*v ; ksum[b,h,d] = sum_s k ----------
__global__ __launch_bounds__(256)
void k_kv(const u16* __restrict__ kb_, const u16* __restrict__ vb_,
          float* __restrict__ kvp, float* __restrict__ ksump) {
    __shared__ float sk[64 * 68], sv[64 * 68];
    int bh = blockIdx.x, b = bh >> 3, h = bh & 7;
    int ch = blockIdx.y;
    int tid = threadIdx.x;
    int d0 = (tid & 15) << 2, m0 = (tid >> 4) << 2;
    float acc[4][4] = {};
    float ks[4] = {0.f, 0.f, 0.f, 0.f};
    size_t gbase = ((size_t)b * SEQ_ + (size_t)ch * 1024) * DM_ + h * 64;

    for (int st = 0; st < 1024; st += 64) {
#pragma unroll
        for (int i = 0; i < 2; ++i) {
            int li = tid + (i << 8);
            int r = li >> 3, c8 = (li & 7) << 3;
            s16x8 kv_ = *(const s16x8*)(kb_ + gbase + (size_t)(st + r) * DM_ + c8);
            s16x8 vv_ = *(const s16x8*)(vb_ + gbase + (size_t)(st + r) * DM_ + c8);
#pragma unroll
            for (int e = 0; e < 8; ++e) {
                sk[r * 68 + c8 + e] = b2f((u16)kv_[e]);
                sv[r * 68 + c8 + e] = b2f((u16)vv_[e]);
            }
        }
        __syncthreads();
        for (int s = 0; s < 64; ++s) {
            f32x4 kd = *(const f32x4*)(sk + s * 68 + d0);
            f32x4 vm = *(const f32x4*)(sv + s * 68 + m0);
#pragma unroll
            for (int i = 0; i < 4; ++i)
#pragma unroll
                for (int j = 0; j < 4; ++j) acc[i][j] += kd[i] * vm[j];
            if ((tid >> 4) == 0) { ks[0] += kd[0]; ks[1] += kd[1]; ks[2] += kd[2]; ks[3] += kd[3]; }
        }
        __syncthreads();
    }
    float* kvo = kvp + ((size_t)ch * 64 + bh) * 4096;
#pragma unroll
    for (int i = 0; i < 4; ++i)
#pragma unroll
        for (int j = 0; j < 4; ++j) kvo[(d0 + i) * 64 + m0 + j] = acc[i][j];
    if ((tid >> 4) == 0) {
        float* kso = ksump + ((size_t)ch * 64 + bh) * 64;
#pragma unroll
        for (int e = 0; e < 4; ++e) kso[d0 + e] = ks[e];
    }
}

// ---------------- attention apply: a = (q . kv) / (q . ksum + eps) --------------------
__global__ __launch_bounds__(256)
void k_attn(const u16* __restrict__ qb_, const float* __restrict__ kvp,
            const float* __restrict__ ksump, u16* __restrict__ ab_) {
    __shared__ float skv[64 * 64];
    __shared__ float sq[64 * 65];
    __shared__ float sks[64];
    int tid = threadIdx.x;
    int bh = blockIdx.y, b = bh >> 3, h = bh & 7;
    int s0 = blockIdx.x << 6;

    for (int i = tid; i < 4096; i += 256) {
        float v = 0.f;
#pragma unroll
        for (int c = 0; c < 4; ++c) v += kvp[((size_t)c * 64 + bh) * 4096 + i];
        skv[i] = v;
    }
    if (tid < 64) {
        float v = 0.f;
#pragma unroll
        for (int c = 0; c < 4; ++c) v += ksump[((size_t)c * 64 + bh) * 64 + tid];
        sks[tid] = v;
    }
#pragma unroll
    for (int i = 0; i < 2; ++i) {
        int li = tid + (i << 8);
        int r = li >> 3, c8 = (li & 7) << 3;
        s16x8 v = *(const s16x8*)(qb_ + ((size_t)b * SEQ_ + s0 + r) * DM_ + h * 64 + c8);
#pragma unroll
        for (int e = 0; e < 8; ++e) sq[r * 65 + c8 + e] = b2f((u16)v[e]);
    }
    __syncthreads();

    int sl = tid >> 2, m0 = (tid & 3) << 4;
    float den = 0.f;
    for (int d = 0; d < 64; ++d) den += sq[sl * 65 + d] * sks[d];
    float z = 1.f / (den + 1e-6f);

    float acc[16] = {};
    for (int d = 0; d < 64; ++d) {
        float qv = sq[sl * 65 + d];
        const f32x4* kp = (const f32x4*)(skv + d * 64 + m0);
#pragma unroll
        for (int j4 = 0; j4 < 4; ++j4) {
            f32x4 kv4 = kp[j4];
#pragma unroll
            for (int e = 0; e < 4; ++e) acc[j4 * 4 + e] += qv * kv4[e];
        }
    }
    u16* op = ab_ + ((size_t)b * SEQ_ + s0 + sl) * DM_ + h * 64 + m0;
    s16x8 o0, o1;
#pragma unroll
    for (int e = 0; e < 8; ++e) o0[e] = (short)f2b(acc[e] * z);
#pragma unroll
    for (int e = 0; e < 8; ++e) o1[e] = (short)f2b(acc[8 + e] * z);
    *(s16x8*)op = o0;
    *(s16x8*)(op + 8) = o1;
}

// ---------------- LayerNorm over 512 (bf16 in -> bf16 out) ----------------------------
__global__ __launch_bounds__(256)
void k_ln(const u16* __restrict__ in, const float* __restrict__ g,
          const float* __restrict__ be, u16* __restrict__ xb) {
    int row = blockIdx.x * 4 + (threadIdx.x >> 6);
    int l = threadIdx.x & 63;
    s16x8 raw = *(const s16x8*)(in + (size_t)row * DM_ + l * 8);
    float x[8];
#pragma unroll
    for (int e = 0; e < 8; ++e) x[e] = b2f((u16)raw[e]);
    float sum = 0.f;
#pragma unroll
    for (int e = 0; e < 8; ++e) sum += x[e];
#pragma unroll
    for (int off = 32; off > 0; off >>= 1) sum += __shfl_xor(sum, off);
    float mu = sum * (1.f / DM_);
    float sq = 0.f;
#pragma unroll
    for (int e = 0; e < 8; ++e) { float d = x[e] - mu; sq += d * d; }
#pragma unroll
    for (int off = 32; off > 0; off >>= 1) sq += __shfl_xor(sq, off);
    float rs = rsqrtf(sq * (1.f / DM_) + 1e-5f);
    int c = l * 8;
    const f32x4* gp = (const f32x4*)(g + c);
    const f32x4* bp = (const f32x4*)(be + c);
    f32x4 g0 = gp[0], g1 = gp[1], e0 = bp[0], e1 = bp[1];
    s16x8 pk;
#pragma unroll
    for (int e = 0; e < 4; ++e) pk[e] = (short)f2b((x[e] - mu) * rs * g0[e] + e0[e]);
#pragma unroll
    for (int e = 0; e < 4; ++e) pk[4 + e] = (short)f2b((x[4 + e] - mu) * rs * g1[e] + e1[e]);
    *(s16x8*)(xb + (size_t)row * DM_ + c) = pk;
}

// ---------------- fused LN2 (layer 1) + final LN + Wout dot ---------------------------
__global__ __launch_bounds__(256)
void k_ln2f(const u16* __restrict__ in, const float* __restrict__ g2,
            const float* __restrict__ b2_, const float* __restrict__ gf,
            const float* __restrict__ bf_, const float* __restrict__ wout,
            const float* __restrict__ bout, float* __restrict__ out) {
    int row = blockIdx.x * 4 + (threadIdx.x >> 6);
    int l = threadIdx.x & 63;
    s16x8 raw = *(const s16x8*)(in + (size_t)row * DM_ + l * 8);
    float x[8];
#pragma unroll
    for (int e = 0; e < 8; ++e) x[e] = b2f((u16)raw[e]);
    float sum = 0.f;
#pragma unroll
    for (int e = 0; e < 8; ++e) sum += x[e];
#pragma unroll
    for (int off = 32; off > 0; off >>= 1) sum += __shfl_xor(sum, off);
    float mu = sum * (1.f / DM_);
    float sq = 0.f;
#pragma unroll
    for (int e = 0; e < 8; ++e) { float d = x[e] - mu; sq += d * d; }
#pragma unroll
    for (int off = 32; off > 0; off >>= 1) sq += __shfl_xor(sq, off);
    float rs = rsqrtf(sq * (1.f / DM_) + 1e-5f);
    int c = l * 8;
    float t[8];
#pragma unroll
    for (int e = 0; e < 8; ++e) t[e] = (x[e] - mu) * rs * g2[c + e] + b2_[c + e];
    float sum2 = 0.f;
#pragma unroll
    for (int e = 0; e < 8; ++e) sum2 += t[e];
#pragma unroll
    for (int off = 32; off > 0; off >>= 1) sum2 += __shfl_xor(sum2, off);
    float mu2 = sum2 * (1.f / DM_);
    float sq2 = 0.f;
#pragma unroll
    for (int e = 0; e < 8; ++e) { float d = t[e] - mu2; sq2 += d * d; }
#pragma unroll
    for (int off = 32; off > 0; off >>= 1) sq2 += __shfl_xor(sq2, off);
    float rs2 = rsqrtf(sq2 * (1.f / DM_) + 1e-5f);
    float p = 0.f;
#pragma unroll
    for (int e = 0; e < 8; ++e)
        p += ((t[e] - mu2) * rs2 * gf[c + e] + bf_[c + e]) * wout[c + e];
#pragma unroll
    for (int off = 32; off > 0; off >>= 1) p += __shfl_xor(p, off);
    if (l == 0) out[row] = p + bout[0];
}

// =======================================================================================
extern "C" void kernel_launch(void* const* d_in, const int* in_sizes, int n_in,
                              void* d_out, int out_size, void* d_ws, size_t ws_size,
                              hipStream_t stream) {
    const float* emb   = (const float*)d_in[0];
    const float* W0    = (const float*)d_in[1];
    const float* b0    = (const float*)d_in[2];
    const float* Wq    = (const float*)d_in[3];
    const float* bq    = (const float*)d_in[4];
    const float* Wk    = (const float*)d_in[5];
    const float* bk    = (const float*)d_in[6];
    const float* Wv    = (const float*)d_in[7];
    const float* bv    = (const float*)d_in[8];
    const float* Wo    = (const float*)d_in[9];
    const float* bo    = (const float*)d_in[10];
    const float* ln1s  = (const float*)d_in[11];
    const float* ln1b  = (const float*)d_in[12];
    const float* W1    = (const float*)d_in[13];
    const float* b1    = (const float*)d_in[14];
    const float* W2    = (const float*)d_in[15];
    const float* b2    = (const float*)d_in[16];
    const float* ln2s  = (const float*)d_in[17];
    const float* ln2b  = (const float*)d_in[18];
    const float* lnfs  = (const float*)d_in[19];
    const float* lnfb  = (const float*)d_in[20];
    const float* Wout  = (const float*)d_in[21];
    const float* bout  = (const float*)d_in[22];
    float* out = (float*)d_out;

    char* ws = (char*)d_ws;
    size_t off = 0;
    auto alloc = [&](size_t bytes) -> void* {
        void* p = ws + off;
        off += (bytes + 255) & ~(size_t)255;
        return p;
    };
    u16* xb   = (u16*)alloc((size_t)BS_ * DM_ * 2);    // 32MB  x (bf16 stream)
    u16* qb   = (u16*)alloc((size_t)BS_ * DM_ * 2);    // 32MB  (rb aliases qb)
    u16* kb   = (u16*)alloc((size_t)BS_ * DM_ * 2);    // 32MB
    u16* vb   = (u16*)alloc((size_t)BS_ * DM_ * 2);    // 32MB
    float* kvp   = (float*)alloc((size_t)4 * 64 * 4096 * 4);
    float* ksump = (float*)alloc((size_t)4 * 64 * 64 * 4);
    u16* wp   = (u16*)alloc((size_t)4521984 * 2);      // weight pool ~9MB

    u16* rb   = qb;    // residual r (written after qb dead)
    u16* ab   = vb;    // attn output (written after vb consumed)
    u16* h1b  = kb;    // 64MB FF hidden = kb+vb regions
    u16* embp = kb;    // 40MB emb bf16 padded = kb+vb regions (dead before QKV)

    u16* W0t  = wp;                          // [512][640]
    u16* Wqkv = wp + 327680;                 // per layer [1536][512]
    u16* Wot  = Wqkv + 2 * 786432;           // per layer [512][512]
    u16* W1t  = Wot + 2 * 262144;            // per layer [1024][512]
    u16* W2t  = W1t + 2 * 524288;            // per layer [512][1024]

    k_tr_all<<<4416, dim3(32, 8), 0, stream>>>(W0, Wq, Wk, Wv, Wo, W1, W2,
                                               W0t, Wqkv, Wot, W1t, W2t);
    k_emb<<<2560, 256, 0, stream>>>(emb, embp);

    // x = emb @ W0 + b0
    k_gemm<0><<<1024, 256, 0, stream>>>(embp, W0t, b0, nullptr, nullptr,
                                        nullptr, xb, nullptr, nullptr, BS_, DM_, FINP_, 4);

    for (int l = 0; l < 2; ++l) {
        // fused QKV: N=1536, feat(elu+1) on q,k
        k_gemm<1><<<3072, 256, 0, stream>>>(xb, Wqkv + (size_t)l * 786432,
                                            bq + l * 512, bk + l * 512, bv + l * 512,
                                            nullptr, qb, kb, vb, BS_, 1536, 512, 12);
        k_kv<<<dim3(64, 4), 256, 0, stream>>>(kb, vb, kvp, ksump);
        k_attn<<<dim3(64, 64), 256, 0, stream>>>(qb, kvp, ksump, ab);
        // r = x + a@Wo + bo
        k_gemm<2><<<1024, 256, 0, stream>>>(ab, Wot + (size_t)l * 262144,
                                            bo + l * 512, nullptr, nullptr,
                                            xb, rb, nullptr, nullptr, BS_, 512, 512, 4);
        k_ln<<<8192, 256, 0, stream>>>(rb, ln1s + l * 512, ln1b + l * 512, xb);
        // h = relu(x@W1+b1)
        k_gemm<3><<<2048, 256, 0, stream>>>(xb, W1t + (size_t)l * 524288,
                                            b1 + l * 1024, nullptr, nullptr,
                                            nullptr, h1b, nullptr, nullptr, BS_, 1024, 512, 8);
        // r = x + h@W2 + b2
        k_gemm<2><<<1024, 256, 0, stream>>>(h1b, W2t + (size_t)l * 524288,
                                            b2 + l * 512, nullptr, nullptr,
                                            xb, rb, nullptr, nullptr, BS_, 512, 1024, 4);
        if (l == 0)
            k_ln<<<8192, 256, 0, stream>>>(rb, ln2s, ln2b, xb);
        else
            k_ln2f<<<8192, 256, 0, stream>>>(rb, ln2s + 512, ln2b + 512,
                                             lnfs, lnfb, Wout, bout, out);
    }
}

// Round 5
// 724.811 us; speedup vs baseline: 1.5352x; 1.1017x over previous
//
#include <hip/hip_runtime.h>
#include <hip/hip_bf16.h>
#include <math.h>

typedef unsigned short u16;
typedef short s16x8 __attribute__((ext_vector_type(8)));
typedef float f32x4 __attribute__((ext_vector_type(4)));

#define BS_   32768      // B*S
#define SEQ_  4096
#define DM_   512
#define FF_   1024
#define FIN_  586
#define FINP_ 640        // emb K padded to multiple of 64
#define PADC  136        // epilogue LDS stride (u16)

__device__ __forceinline__ u16 f2b(float f) {
    __hip_bfloat16 h = __float2bfloat16(f);      // RNE, hw v_cvt on gfx950
    return *reinterpret_cast<u16*>(&h);
}
__device__ __forceinline__ float b2f(u16 h) {
    union { unsigned u; float f; } a; a.u = ((unsigned)h) << 16;
    return a.f;
}

typedef __attribute__((address_space(1))) const unsigned gu32;
typedef __attribute__((address_space(3))) unsigned lu32;
__device__ __forceinline__ void glds16(const void* g, void* l) {
    __builtin_amdgcn_global_load_lds((gu32*)g, (lu32*)l, 16, 0, 0);
}

// ---------------- batched weight transpose + bf16 convert (one launch) ----------------
__device__ __forceinline__ void tr_tile(const float* __restrict__ W, u16* __restrict__ Wt,
                                        int K, int N, int Kpad, int tidx, int ktiles,
                                        float (*t)[33]) {
    int kb = (tidx % ktiles) << 5, nb = (tidx / ktiles) << 5;
    int tx = threadIdx.x, ty = threadIdx.y;          // 32 x 8
#pragma unroll
    for (int j = 0; j < 32; j += 8) {
        int k = kb + ty + j;
        t[ty + j][tx] = (k < K) ? W[(size_t)k * N + nb + tx] : 0.f;
    }
    __syncthreads();
#pragma unroll
    for (int j = 0; j < 32; j += 8) {
        Wt[(size_t)(nb + ty + j) * Kpad + kb + tx] = f2b(t[tx][ty + j]);
    }
}

__global__ void k_tr_all(const float* __restrict__ W0, const float* __restrict__ Wq,
                         const float* __restrict__ Wk, const float* __restrict__ Wv,
                         const float* __restrict__ Wo, const float* __restrict__ W1,
                         const float* __restrict__ W2,
                         u16* __restrict__ W0t, u16* __restrict__ Wqkv,
                         u16* __restrict__ Wot, u16* __restrict__ W1t,
                         u16* __restrict__ W2t) {
    __shared__ float t[32][33];
    int b = blockIdx.x;
    if (b < 320) { tr_tile(W0, W0t, FIN_, DM_, FINP_, b, 20, t); return; }   // 20x16 tiles
    b -= 320;
    int l = b >> 11;              // 2048 tiles per layer
    int r = b & 2047;
    if (r < 768) {                // q,k,v : 256 tiles each
        int sel = r >> 8, ti = r & 255;
        const float* src = sel == 0 ? Wq : (sel == 1 ? Wk : Wv);
        tr_tile(src + (size_t)l * 262144, Wqkv + (size_t)l * 786432 + (size_t)sel * 262144,
                512, 512, 512, ti, 16, t);
    } else if (r < 1024) {
        tr_tile(Wo + (size_t)l * 262144, Wot + (size_t)l * 262144, 512, 512, 512, r - 768, 16, t);
    } else if (r < 1536) {
        tr_tile(W1 + (size_t)l * 524288, W1t + (size_t)l * 524288, 512, 1024, 512, r - 1024, 16, t);
    } else {
        tr_tile(W2 + (size_t)l * 524288, W2t + (size_t)l * 524288, 1024, 512, 1024, r - 1536, 32, t);
    }
}

// ---------------- embeddings -> bf16 padded [BS][640] ---------------------------------
__global__ __launch_bounds__(256)
void k_emb(const float* __restrict__ E, u16* __restrict__ Ep) {
    const int total8 = BS_ * (FINP_ / 8);
    for (int i = blockIdx.x * 256 + threadIdx.x; i < total8; i += gridDim.x * 256) {
        int rr = i / (FINP_ / 8), c = (i % (FINP_ / 8)) * 8;
        const float* rp = E + (size_t)rr * FIN_ + c;
        s16x8 o;
#pragma unroll
        for (int e = 0; e < 8; ++e) {
            float v = (c + e < FIN_) ? rp[e] : 0.f;
            o[e] = (short)f2b(v);
        }
        *(s16x8*)(Ep + (size_t)rr * FINP_ + c) = o;
    }
}

// ---------------- MFMA GEMM: BK=64, dbuf 2-phase prefetch, T2 swizzle, coalesced epi --
// 128x128 tile, global_load_lds 16B (linear dest, swizzled SOURCE), XCD swizzle.
// 2-phase: issue STAGE(buf^1, t+1) BEFORE ds_read+MFMA on buf[cur]; one barrier/iter.
// EPI: 0 = bias only, 1 = QKV split (feat on q,k), 2 = residual-add, 3 = relu
template<int EPI>
__global__ __launch_bounds__(256)
void k_gemm(const u16* __restrict__ A, const u16* __restrict__ Bt,
            const float* __restrict__ bias0, const float* __restrict__ bias1,
            const float* __restrict__ bias2,
            const u16* __restrict__ resid,
            u16* __restrict__ out0, u16* __restrict__ out1, u16* __restrict__ out2,
            int M, int N, int K, int NT) {
    __shared__ __align__(16) u16 smem[32768];      // 64KB: 2 x (sA[128][64] | sB[128][64])
    u16* sC = smem;                                 // [64][PADC] epilogue union (post-loop)

    const int nwg = gridDim.x;
    const int cpx = nwg >> 3;                      // nwg % 8 == 0 always here
    const int wg = (blockIdx.x & 7) * cpx + (blockIdx.x >> 3);
    const int mt = wg / NT, nt = wg - mt * NT;
    const int m0 = mt << 7, n0 = nt << 7;
    const int tid = threadIdx.x;
    const int w = tid >> 6, l = tid & 63;
    const int wm = (w >> 1) << 6, wn = (w & 1) << 6;
    const int lr = l & 15, lg = l >> 4;

    // staging: 256 thr x 16B = 32 rows of 128B per call; 4 calls per operand tile
    const int srow = tid >> 3;                     // 0..31
    const int swzk = (((tid & 7) ^ (tid >> 3)) & 7) << 3;   // swizzled k-offset (elems)
    const u16* Ap = A + (size_t)(m0 + srow) * K + swzk;
    const u16* Bp = Bt + (size_t)(n0 + srow) * K + swzk;

    // read-side swizzled chunk offsets (elems): logical chunk c, row-phase lr&7
    const int rph = lr & 7;
    const int axk0 = ((0 + lg) ^ rph) << 3;
    const int axk1 = ((4 + lg) ^ rph) << 3;

    f32x4 acc[4][4] = {};
    const int ntile = K >> 6;

    // prologue: stage tile 0 into buf 0
    {
        u16* sAp = smem + tid * 8;
        u16* sBp = smem + 8192 + tid * 8;
#pragma unroll
        for (int g = 0; g < 4; ++g) {
            glds16(Ap + (size_t)(g * 32) * K, sAp + g * 2048);
            glds16(Bp + (size_t)(g * 32) * K, sBp + g * 2048);
        }
    }
    __syncthreads();

    int cur = 0;
    for (int t = 0; t < ntile; ++t) {
        // issue next-tile loads into the other buffer (overlaps with MFMA below)
        if (t + 1 < ntile) {
            const int k1 = (t + 1) << 6;
            u16* sAp = smem + ((cur ^ 1) << 14) + tid * 8;
            u16* sBp = sAp + 8192;
#pragma unroll
            for (int g = 0; g < 4; ++g) {
                glds16(Ap + (size_t)(g * 32) * K + k1, sAp + g * 2048);
                glds16(Bp + (size_t)(g * 32) * K + k1, sBp + g * 2048);
            }
        }
        const u16* sA = smem + (cur << 14);
        const u16* sB = sA + 8192;
        s16x8 af[4], bfr[4];
#pragma unroll
        for (int i = 0; i < 4; ++i) af[i] = *(const s16x8*)(sA + (wm + i * 16 + lr) * 64 + axk0);
#pragma unroll
        for (int j = 0; j < 4; ++j) bfr[j] = *(const s16x8*)(sB + (wn + j * 16 + lr) * 64 + axk0);
#pragma unroll
        for (int i = 0; i < 4; ++i)
#pragma unroll
            for (int j = 0; j < 4; ++j)
                acc[i][j] = __builtin_amdgcn_mfma_f32_16x16x32_bf16(af[i], bfr[j], acc[i][j], 0, 0, 0);
#pragma unroll
        for (int i = 0; i < 4; ++i) af[i] = *(const s16x8*)(sA + (wm + i * 16 + lr) * 64 + axk1);
#pragma unroll
        for (int j = 0; j < 4; ++j) bfr[j] = *(const s16x8*)(sB + (wn + j * 16 + lr) * 64 + axk1);
#pragma unroll
        for (int i = 0; i < 4; ++i)
#pragma unroll
            for (int j = 0; j < 4; ++j)
                acc[i][j] = __builtin_amdgcn_mfma_f32_16x16x32_bf16(af[i], bfr[j], acc[i][j], 0, 0, 0);
        __syncthreads();                           // drains vmcnt(0): next tile ready
        cur ^= 1;
    }

    // ---- epilogue: 2 passes of 64 rows through sC (union with staging) ----
    const int seg = (EPI == 1) ? (n0 >> 9) : 0;     // 0=q 1=k 2=v when N=1536
    const float* bias = (EPI == 1) ? (seg == 0 ? bias0 : (seg == 1 ? bias1 : bias2)) : bias0;
    u16* dst = (EPI == 1) ? (seg == 0 ? out0 : (seg == 1 ? out1 : out2)) : out0;
    const int ldo = (EPI == 1) ? 512 : N;
    const int ncol0 = (EPI == 1) ? (n0 & 511) : n0;

#pragma unroll
    for (int pass = 0; pass < 2; ++pass) {
        if ((w >> 1) == pass) {                     // waves owning rows pass*64..+63
#pragma unroll
            for (int j = 0; j < 4; ++j) {
                const int col = wn + j * 16 + lr;
                const float bv = bias[ncol0 + col];
#pragma unroll
                for (int i = 0; i < 4; ++i)
#pragma unroll
                    for (int r = 0; r < 4; ++r) {
                        const int row = i * 16 + (lg << 2) + r;     // local 0..63
                        sC[row * PADC + col] = f2b(acc[i][j][r] + bv);
                    }
            }
        }
        __syncthreads();
        const int rbase = m0 + (pass << 6);
#pragma unroll
        for (int t = 0; t < 4; ++t) {
            const int idx = t * 256 + tid;          // 0..1023
            const int row = idx >> 4;
            const int c8 = (idx & 15) << 3;
            s16x8 v8 = *(const s16x8*)(sC + row * PADC + c8);
            size_t gaddr = (size_t)(rbase + row) * ldo + ncol0 + c8;
            s16x8 o = v8;
            if constexpr (EPI == 1) {
                if (seg < 2) {
#pragma unroll
                    for (int e = 0; e < 8; ++e) {
                        float v = b2f((u16)v8[e]);
                        v = (v > 0.f) ? v + 1.f : __expf(v);   // elu+1
                        o[e] = (short)f2b(v);
                    }
                }
            } else if constexpr (EPI == 2) {
                s16x8 rv = *(const s16x8*)(resid + gaddr);
#pragma unroll
                for (int e = 0; e < 8; ++e)
                    o[e] = (short)f2b(b2f((u16)v8[e]) + b2f((u16)rv[e]));
            } else if constexpr (EPI == 3) {
#pragma unroll
                for (int e = 0; e < 8; ++e)
                    o[e] = (short)f2b(fmaxf(b2f((u16)v8[e]), 0.f));
            }
            *(s16x8*)(dst + gaddr) = o;
        }
        __syncthreads();
    }
}

// ---------------- kv einsum: kv[b,h,d,m] = sum_s k*v ; ksum[b,h,d] = sum_s k ----------
__global__ __launch_bounds__(256)
void k_kv(const u16* __restrict__ kb_, const u16* __restrict__ vb_,
          float* __restrict__ kvp, float* __restrict__ ksump) {
    __shared__ float sk[64 * 68], sv[64 * 68];
    int bh = blockIdx.x, b = bh >> 3, h = bh & 7;
    int ch = blockIdx.y;
    int tid = threadIdx.x;
    int d0 = (tid & 15) << 2, m0 = (tid >> 4) << 2;
    float acc[4][4] = {};
    float ks[4] = {0.f, 0.f, 0.f, 0.f};
    size_t gbase = ((size_t)b * SEQ_ + (size_t)ch * 1024) * DM_ + h * 64;

    for (int st = 0; st < 1024; st += 64) {
#pragma unroll
        for (int i = 0; i < 2; ++i) {
            int li = tid + (i << 8);
            int r = li >> 3, c8 = (li & 7) << 3;
            s16x8 kv_ = *(const s16x8*)(kb_ + gbase + (size_t)(st + r) * DM_ + c8);
            s16x8 vv_ = *(const s16x8*)(vb_ + gbase + (size_t)(st + r) * DM_ + c8);
#pragma unroll
            for (int e = 0; e < 8; ++e) {
                sk[r * 68 + c8 + e] = b2f((u16)kv_[e]);
                sv[r * 68 + c8 + e] = b2f((u16)vv_[e]);
            }
        }
        __syncthreads();
        for (int s = 0; s < 64; ++s) {
            f32x4 kd = *(const f32x4*)(sk + s * 68 + d0);
            f32x4 vm = *(const f32x4*)(sv + s * 68 + m0);
#pragma unroll
            for (int i = 0; i < 4; ++i)
#pragma unroll
                for (int j = 0; j < 4; ++j) acc[i][j] += kd[i] * vm[j];
            if ((tid >> 4) == 0) { ks[0] += kd[0]; ks[1] += kd[1]; ks[2] += kd[2]; ks[3] += kd[3]; }
        }
        __syncthreads();
    }
    float* kvo = kvp + ((size_t)ch * 64 + bh) * 4096;
#pragma unroll
    for (int i = 0; i < 4; ++i)
#pragma unroll
        for (int j = 0; j < 4; ++j) kvo[(d0 + i) * 64 + m0 + j] = acc[i][j];
    if ((tid >> 4) == 0) {
        float* kso = ksump + ((size_t)ch * 64 + bh) * 64;
#pragma unroll
        for (int e = 0; e < 4; ++e) kso[d0 + e] = ks[e];
    }
}

// ---------------- attention apply: a = (q . kv) / (q . ksum + eps) --------------------
__global__ __launch_bounds__(256)
void k_attn(const u16* __restrict__ qb_, const float* __restrict__ kvp,
            const float* __restrict__ ksump, u16* __restrict__ ab_) {
    __shared__ float skv[64 * 64];
    __shared__ float sq[64 * 65];
    __shared__ float sks[64];
    int tid = threadIdx.x;
    int bh = blockIdx.y, b = bh >> 3, h = bh & 7;
    int s0 = blockIdx.x << 6;

    for (int i = tid; i < 4096; i += 256) {
        float v = 0.f;
#pragma unroll
        for (int c = 0; c < 4; ++c) v += kvp[((size_t)c * 64 + bh) * 4096 + i];
        skv[i] = v;
    }
    if (tid < 64) {
        float v = 0.f;
#pragma unroll
        for (int c = 0; c < 4; ++c) v += ksump[((size_t)c * 64 + bh) * 64 + tid];
        sks[tid] = v;
    }
#pragma unroll
    for (int i = 0; i < 2; ++i) {
        int li = tid + (i << 8);
        int r = li >> 3, c8 = (li & 7) << 3;
        s16x8 v = *(const s16x8*)(qb_ + ((size_t)b * SEQ_ + s0 + r) * DM_ + h * 64 + c8);
#pragma unroll
        for (int e = 0; e < 8; ++e) sq[r * 65 + c8 + e] = b2f((u16)v[e]);
    }
    __syncthreads();

    int sl = tid >> 2, m0 = (tid & 3) << 4;
    float den = 0.f;
    for (int d = 0; d < 64; ++d) den += sq[sl * 65 + d] * sks[d];
    float z = 1.f / (den + 1e-6f);

    float acc[16] = {};
    for (int d = 0; d < 64; ++d) {
        float qv = sq[sl * 65 + d];
        const f32x4* kp = (const f32x4*)(skv + d * 64 + m0);
#pragma unroll
        for (int j4 = 0; j4 < 4; ++j4) {
            f32x4 kv4 = kp[j4];
#pragma unroll
            for (int e = 0; e < 4; ++e) acc[j4 * 4 + e] += qv * kv4[e];
        }
    }
    u16* op = ab_ + ((size_t)b * SEQ_ + s0 + sl) * DM_ + h * 64 + m0;
    s16x8 o0, o1;
#pragma unroll
    for (int e = 0; e < 8; ++e) o0[e] = (short)f2b(acc[e] * z);
#pragma unroll
    for (int e = 0; e < 8; ++e) o1[e] = (short)f2b(acc[8 + e] * z);
    *(s16x8*)op = o0;
    *(s16x8*)(op + 8) = o1;
}

// ---------------- LayerNorm over 512 (bf16 in -> bf16 out) ----------------------------
__global__ __launch_bounds__(256)
void k_ln(const u16* __restrict__ in, const float* __restrict__ g,
          const float* __restrict__ be, u16* __restrict__ xb) {
    int row = blockIdx.x * 4 + (threadIdx.x >> 6);
    int l = threadIdx.x & 63;
    s16x8 raw = *(const s16x8*)(in + (size_t)row * DM_ + l * 8);
    float x[8];
#pragma unroll
    for (int e = 0; e < 8; ++e) x[e] = b2f((u16)raw[e]);
    float sum = 0.f;
#pragma unroll
    for (int e = 0; e < 8; ++e) sum += x[e];
#pragma unroll
    for (int off = 32; off > 0; off >>= 1) sum += __shfl_xor(sum, off);
    float mu = sum * (1.f / DM_);
    float sq = 0.f;
#pragma unroll
    for (int e = 0; e < 8; ++e) { float d = x[e] - mu; sq += d * d; }
#pragma unroll
    for (int off = 32; off > 0; off >>= 1) sq += __shfl_xor(sq, off);
    float rs = rsqrtf(sq * (1.f / DM_) + 1e-5f);
    int c = l * 8;
    const f32x4* gp = (const f32x4*)(g + c);
    const f32x4* bp = (const f32x4*)(be + c);
    f32x4 g0 = gp[0], g1 = gp[1], e0 = bp[0], e1 = bp[1];
    s16x8 pk;
#pragma unroll
    for (int e = 0; e < 4; ++e) pk[e] = (short)f2b((x[e] - mu) * rs * g0[e] + e0[e]);
#pragma unroll
    for (int e = 0; e < 4; ++e) pk[4 + e] = (short)f2b((x[4 + e] - mu) * rs * g1[e] + e1[e]);
    *(s16x8*)(xb + (size_t)row * DM_ + c) = pk;
}

// ---------------- fused LN2 (layer 1) + final LN + Wout dot ---------------------------
__global__ __launch_bounds__(256)
void k_ln2f(const u16* __restrict__ in, const float* __restrict__ g2,
            const float* __restrict__ b2_, const float* __restrict__ gf,
            const float* __restrict__ bf_, const float* __restrict__ wout,
            const float* __restrict__ bout, float* __restrict__ out) {
    int row = blockIdx.x * 4 + (threadIdx.x >> 6);
    int l = threadIdx.x & 63;
    s16x8 raw = *(const s16x8*)(in + (size_t)row * DM_ + l * 8);
    float x[8];
#pragma unroll
    for (int e = 0; e < 8; ++e) x[e] = b2f((u16)raw[e]);
    float sum = 0.f;
#pragma unroll
    for (int e = 0; e < 8; ++e) sum += x[e];
#pragma unroll
    for (int off = 32; off > 0; off >>= 1) sum += __shfl_xor(sum, off);
    float mu = sum * (1.f / DM_);
    float sq = 0.f;
#pragma unroll
    for (int e = 0; e < 8; ++e) { float d = x[e] - mu; sq += d * d; }
#pragma unroll
    for (int off = 32; off > 0; off >>= 1) sq += __shfl_xor(sq, off);
    float rs = rsqrtf(sq * (1.f / DM_) + 1e-5f);
    int c = l * 8;
    float t[8];
#pragma unroll
    for (int e = 0; e < 8; ++e) t[e] = (x[e] - mu) * rs * g2[c + e] + b2_[c + e];
    float sum2 = 0.f;
#pragma unroll
    for (int e = 0; e < 8; ++e) sum2 += t[e];
#pragma unroll
    for (int off = 32; off > 0; off >>= 1) sum2 += __shfl_xor(sum2, off);
    float mu2 = sum2 * (1.f / DM_);
    float sq2 = 0.f;
#pragma unroll
    for (int e = 0; e < 8; ++e) { float d = t[e] - mu2; sq2 += d * d; }
#pragma unroll
    for (int off = 32; off > 0; off >>= 1) sq2 += __shfl_xor(sq2, off);
    float rs2 = rsqrtf(sq2 * (1.f / DM_) + 1e-5f);
    float p = 0.f;
#pragma unroll
    for (int e = 0; e < 8; ++e)
        p += ((t[e] - mu2) * rs2 * gf[c + e] + bf_[c + e]) * wout[c + e];
#pragma unroll
    for (int off = 32; off > 0; off >>= 1) p += __shfl_xor(p, off);
    if (l == 0) out[row] = p + bout[0];
}

// =======================================================================================
extern "C" void kernel_launch(void* const* d_in, const int* in_sizes, int n_in,
                              void* d_out, int out_size, void* d_ws, size_t ws_size,
                              hipStream_t stream) {
    const float* emb   = (const float*)d_in[0];
    const float* W0    = (const float*)d_in[1];
    const float* b0    = (const float*)d_in[2];
    const float* Wq    = (const float*)d_in[3];
    const float* bq    = (const float*)d_in[4];
    const float* Wk    = (const float*)d_in[5];
    const float* bk    = (const float*)d_in[6];
    const float* Wv    = (const float*)d_in[7];
    const float* bv    = (const float*)d_in[8];
    const float* Wo    = (const float*)d_in[9];
    const float* bo    = (const float*)d_in[10];
    const float* ln1s  = (const float*)d_in[11];
    const float* ln1b  = (const float*)d_in[12];
    const float* W1    = (const float*)d_in[13];
    const float* b1    = (const float*)d_in[14];
    const float* W2    = (const float*)d_in[15];
    const float* b2    = (const float*)d_in[16];
    const float* ln2s  = (const float*)d_in[17];
    const float* ln2b  = (const float*)d_in[18];
    const float* lnfs  = (const float*)d_in[19];
    const float* lnfb  = (const float*)d_in[20];
    const float* Wout  = (const float*)d_in[21];
    const float* bout  = (const float*)d_in[22];
    float* out = (float*)d_out;

    char* ws = (char*)d_ws;
    size_t off = 0;
    auto alloc = [&](size_t bytes) -> void* {
        void* p = ws + off;
        off += (bytes + 255) & ~(size_t)255;
        return p;
    };
    u16* xb   = (u16*)alloc((size_t)BS_ * DM_ * 2);    // 32MB  x (bf16 stream)
    u16* qb   = (u16*)alloc((size_t)BS_ * DM_ * 2);    // 32MB  (rb aliases qb)
    u16* kb   = (u16*)alloc((size_t)BS_ * DM_ * 2);    // 32MB
    u16* vb   = (u16*)alloc((size_t)BS_ * DM_ * 2);    // 32MB
    float* kvp   = (float*)alloc((size_t)4 * 64 * 4096 * 4);
    float* ksump = (float*)alloc((size_t)4 * 64 * 64 * 4);
    u16* wp   = (u16*)alloc((size_t)4521984 * 2);      // weight pool ~9MB

    u16* rb   = qb;    // residual r (written after qb dead)
    u16* ab   = vb;    // attn output (written after vb consumed)
    u16* h1b  = kb;    // 64MB FF hidden = kb+vb regions
    u16* embp = kb;    // 40MB emb bf16 padded = kb+vb regions (dead before QKV)

    u16* W0t  = wp;                          // [512][640]
    u16* Wqkv = wp + 327680;                 // per layer [1536][512]
    u16* Wot  = Wqkv + 2 * 786432;           // per layer [512][512]
    u16* W1t  = Wot + 2 * 262144;            // per layer [1024][512]
    u16* W2t  = W1t + 2 * 524288;            // per layer [512][1024]

    k_tr_all<<<4416, dim3(32, 8), 0, stream>>>(W0, Wq, Wk, Wv, Wo, W1, W2,
                                               W0t, Wqkv, Wot, W1t, W2t);
    k_emb<<<2560, 256, 0, stream>>>(emb, embp);

    // x = emb @ W0 + b0
    k_gemm<0><<<1024, 256, 0, stream>>>(embp, W0t, b0, nullptr, nullptr,
                                        nullptr, xb, nullptr, nullptr, BS_, DM_, FINP_, 4);

    for (int l = 0; l < 2; ++l) {
        // fused QKV: N=1536, feat(elu+1) on q,k
        k_gemm<1><<<3072, 256, 0, stream>>>(xb, Wqkv + (size_t)l * 786432,
                                            bq + l * 512, bk + l * 512, bv + l * 512,
                                            nullptr, qb, kb, vb, BS_, 1536, 512, 12);
        k_kv<<<dim3(64, 4), 256, 0, stream>>>(kb, vb, kvp, ksump);
        k_attn<<<dim3(64, 64), 256, 0, stream>>>(qb, kvp, ksump, ab);
        // r = x + a@Wo + bo
        k_gemm<2><<<1024, 256, 0, stream>>>(ab, Wot + (size_t)l * 262144,
                                            bo + l * 512, nullptr, nullptr,
                                            xb, rb, nullptr, nullptr, BS_, 512, 512, 4);
        k_ln<<<8192, 256, 0, stream>>>(rb, ln1s + l * 512, ln1b + l * 512, xb);
        // h = relu(x@W1+b1)
        k_gemm<3><<<2048, 256, 0, stream>>>(xb, W1t + (size_t)l * 524288,
                                            b1 + l * 1024, nullptr, nullptr,
                                            nullptr, h1b, nullptr, nullptr, BS_, 1024, 512, 8);
        // r = x + h@W2 + b2
        k_gemm<2><<<1024, 256, 0, stream>>>(h1b, W2t + (size_t)l * 524288,
                                            b2 + l * 512, nullptr, nullptr,
                                            xb, rb, nullptr, nullptr, BS_, 512, 1024, 4);
        if (l == 0)
            k_ln<<<8192, 256, 0, stream>>>(rb, ln2s, ln2b, xb);
        else
            k_ln2f<<<8192, 256, 0, stream>>>(rb, ln2s + 512, ln2b + 512,
                                             lnfs, lnfb, Wout, bout, out);
    }
}

// Round 6
// 709.920 us; speedup vs baseline: 1.5674x; 1.0210x over previous
//
#include <hip/hip_runtime.h>
#include <hip/hip_bf16.h>
#include <math.h>

typedef unsigned short u16;
typedef short s16x8 __attribute__((ext_vector_type(8)));
typedef float f32x4 __attribute__((ext_vector_type(4)));

#define BS_   32768      // B*S
#define SEQ_  4096
#define DM_   512
#define FF_   1024
#define FIN_  586
#define FINP_ 640        // emb K padded to multiple of 64
#define PADE  264        // epilogue LDS stride (u16) for 256-wide tile

__device__ __forceinline__ u16 f2b(float f) {
    __hip_bfloat16 h = __float2bfloat16(f);      // RNE, hw v_cvt on gfx950
    return *reinterpret_cast<u16*>(&h);
}
__device__ __forceinline__ float b2f(u16 h) {
    union { unsigned u; float f; } a; a.u = ((unsigned)h) << 16;
    return a.f;
}

typedef __attribute__((address_space(1))) const unsigned gu32;
typedef __attribute__((address_space(3))) unsigned lu32;
__device__ __forceinline__ void glds16(const void* g, void* l) {
    __builtin_amdgcn_global_load_lds((gu32*)g, (lu32*)l, 16, 0, 0);
}

// ---------------- batched weight transpose + bf16 convert (one launch) ----------------
__device__ __forceinline__ void tr_tile(const float* __restrict__ W, u16* __restrict__ Wt,
                                        int K, int N, int Kpad, int tidx, int ktiles,
                                        float (*t)[33]) {
    int kb = (tidx % ktiles) << 5, nb = (tidx / ktiles) << 5;
    int tx = threadIdx.x, ty = threadIdx.y;          // 32 x 8
#pragma unroll
    for (int j = 0; j < 32; j += 8) {
        int k = kb + ty + j;
        t[ty + j][tx] = (k < K) ? W[(size_t)k * N + nb + tx] : 0.f;
    }
    __syncthreads();
#pragma unroll
    for (int j = 0; j < 32; j += 8) {
        Wt[(size_t)(nb + ty + j) * Kpad + kb + tx] = f2b(t[tx][ty + j]);
    }
}

__global__ void k_tr_all(const float* __restrict__ W0, const float* __restrict__ Wq,
                         const float* __restrict__ Wk, const float* __restrict__ Wv,
                         const float* __restrict__ Wo, const float* __restrict__ W1,
                         const float* __restrict__ W2,
                         u16* __restrict__ W0t, u16* __restrict__ Wqkv,
                         u16* __restrict__ Wot, u16* __restrict__ W1t,
                         u16* __restrict__ W2t) {
    __shared__ float t[32][33];
    int b = blockIdx.x;
    if (b < 320) { tr_tile(W0, W0t, FIN_, DM_, FINP_, b, 20, t); return; }   // 20x16 tiles
    b -= 320;
    int l = b >> 11;              // 2048 tiles per layer
    int r = b & 2047;
    if (r < 768) {                // q,k,v : 256 tiles each
        int sel = r >> 8, ti = r & 255;
        const float* src = sel == 0 ? Wq : (sel == 1 ? Wk : Wv);
        tr_tile(src + (size_t)l * 262144, Wqkv + (size_t)l * 786432 + (size_t)sel * 262144,
                512, 512, 512, ti, 16, t);
    } else if (r < 1024) {
        tr_tile(Wo + (size_t)l * 262144, Wot + (size_t)l * 262144, 512, 512, 512, r - 768, 16, t);
    } else if (r < 1536) {
        tr_tile(W1 + (size_t)l * 524288, W1t + (size_t)l * 524288, 512, 1024, 512, r - 1024, 16, t);
    } else {
        tr_tile(W2 + (size_t)l * 524288, W2t + (size_t)l * 524288, 1024, 512, 1024, r - 1536, 32, t);
    }
}

// ---------------- embeddings -> bf16 padded [BS][640] ---------------------------------
__global__ __launch_bounds__(256)
void k_emb(const float* __restrict__ E, u16* __restrict__ Ep) {
    const int total8 = BS_ * (FINP_ / 8);
    for (int i = blockIdx.x * 256 + threadIdx.x; i < total8; i += gridDim.x * 256) {
        int rr = i / (FINP_ / 8), c = (i % (FINP_ / 8)) * 8;
        const float* rp = E + (size_t)rr * FIN_ + c;
        s16x8 o;
#pragma unroll
        for (int e = 0; e < 8; ++e) {
            float v = (c + e < FIN_) ? rp[e] : 0.f;
            o[e] = (short)f2b(v);
        }
        *(s16x8*)(Ep + (size_t)rr * FINP_ + c) = o;
    }
}

// ---------------- MFMA GEMM: 256x256 tile, 8 waves, 4-phase/K-tile schedule -----------
// BK=64, 2x double-buffered LDS (128KB), glds 16B (linear dest, swizzled SOURCE),
// XCD-swizzled grid. Per tile: 4 quadrant-phases {ds_read | stage | 16 MFMA | barrier}.
// All 8 stages for tile t+1 issued in phases 0-1, into buf d^1 (race-free: d^1's
// readers done at previous __syncthreads; tile-end __syncthreads drains vmcnt(0)).
// EPI: 0 = bias only, 1 = QKV split (feat on q,k), 2 = residual-add, 3 = relu
template<int EPI>
__global__ __launch_bounds__(512, 2)
void k_gemm(const u16* __restrict__ A, const u16* __restrict__ Bt,
            const float* __restrict__ bias0, const float* __restrict__ bias1,
            const float* __restrict__ bias2,
            const u16* __restrict__ resid,
            u16* __restrict__ out0, u16* __restrict__ out1, u16* __restrict__ out2,
            int M, int N, int K, int NT) {
    // u16 layout: A buf0 [0,16384) | A buf1 [16384,32768) | B buf0 [32768,49152) | B buf1 [49152,65536)
    __shared__ __align__(16) u16 smem[65536];      // 128 KB

    const int nwg = gridDim.x;
    const int cpx = nwg >> 3;                      // nwg % 8 == 0 for all launches here
    const int wg = (blockIdx.x & 7) * cpx + (blockIdx.x >> 3);
    const int mt = wg / NT, ntl = wg - mt * NT;
    const int m0 = mt << 8, n0 = ntl << 8;
    const int tid = threadIdx.x;
    const int wid = tid >> 6, l = tid & 63;
    const int wr = wid >> 2, wc = wid & 3;         // 2M x 4N waves; wave tile 128x64
    const int lr = l & 15, lg = l >> 4;

    // staging map: 512 thr x 16B = 64 rows of 128B per call; 4 calls per operand tile
    const int srow = tid >> 3;                     // 0..63
    const int gchunk = (((tid & 7) ^ (srow & 7)) & 7) << 3;   // swizzled source k-offset
    const u16* Abase = A + (size_t)(m0 + srow) * K + gchunk;
    const u16* Bbase = Bt + (size_t)(n0 + srow) * K + gchunk;

    auto stageA = [&](int d, int tt) {
        u16* dst = smem + d * 16384 + tid * 8;
        const u16* src = Abase + (size_t)tt * 64;
#pragma unroll
        for (int hg = 0; hg < 4; ++hg)             // rows hg*64..hg*64+63
            glds16(src + (size_t)(hg * 64) * K, dst + hg * 4096);
    };
    auto stageB = [&](int d, int tt) {
        u16* dst = smem + 32768 + d * 16384 + tid * 8;
        const u16* src = Bbase + (size_t)tt * 64;
#pragma unroll
        for (int hg = 0; hg < 4; ++hg)
            glds16(src + (size_t)(hg * 64) * K, dst + hg * 4096);
    };

    // read-side swizzled chunk offsets (elems); row&7 == lr&7 for all frag rows
    const int aswz0 = ((0 + lg) ^ (lr & 7)) << 3;  // k-half 0
    const int aswz1 = ((4 + lg) ^ (lr & 7)) << 3;  // k-half 1

    f32x4 acc[8][4] = {};
    const int ntile = K >> 6;

    stageA(0, 0);
    stageB(0, 0);
    __syncthreads();                               // vmcnt(0) drain: tile 0 ready

    s16x8 bf0[4], bf1[4];
    for (int t = 0; t < ntile; ++t) {
        const int d = t & 1, nd = d ^ 1;
        const int abase = d * 16384 + wr * 8192;                       // A half = wr
        const int bbase = 32768 + d * 16384 + (wc >> 1) * 8192 + ((wc & 1) * 64 + lr) * 64;
#pragma unroll
        for (int q = 0; q < 4; ++q) {
            const int r0 = (2 * q) * 16 + lr;
            const int r1 = (2 * q + 1) * 16 + lr;
            s16x8 a00 = *(const s16x8*)(smem + abase + r0 * 64 + aswz0);
            s16x8 a01 = *(const s16x8*)(smem + abase + r0 * 64 + aswz1);
            s16x8 a10 = *(const s16x8*)(smem + abase + r1 * 64 + aswz0);
            s16x8 a11 = *(const s16x8*)(smem + abase + r1 * 64 + aswz1);
            if (q == 0) {
#pragma unroll
                for (int fc = 0; fc < 4; ++fc) {
                    bf0[fc] = *(const s16x8*)(smem + bbase + fc * 1024 + aswz0);
                    bf1[fc] = *(const s16x8*)(smem + bbase + fc * 1024 + aswz1);
                }
                if (t + 1 < ntile) stageA(nd, t + 1);
            } else if (q == 1) {
                if (t + 1 < ntile) stageB(nd, t + 1);
            }
            __builtin_amdgcn_s_setprio(1);
#pragma unroll
            for (int fc = 0; fc < 4; ++fc) {
                acc[2 * q][fc]     = __builtin_amdgcn_mfma_f32_16x16x32_bf16(a00, bf0[fc], acc[2 * q][fc], 0, 0, 0);
                acc[2 * q][fc]     = __builtin_amdgcn_mfma_f32_16x16x32_bf16(a01, bf1[fc], acc[2 * q][fc], 0, 0, 0);
                acc[2 * q + 1][fc] = __builtin_amdgcn_mfma_f32_16x16x32_bf16(a10, bf0[fc], acc[2 * q + 1][fc], 0, 0, 0);
                acc[2 * q + 1][fc] = __builtin_amdgcn_mfma_f32_16x16x32_bf16(a11, bf1[fc], acc[2 * q + 1][fc], 0, 0, 0);
            }
            __builtin_amdgcn_s_setprio(0);
            if (q < 3) __builtin_amdgcn_s_barrier();   // phase barrier: no vmcnt drain
            else __syncthreads();                      // tile end: drains vmcnt(0) -> t+1 ready
        }
    }

    // ---- epilogue: 2 passes of 128 rows through sC (smem reuse; [128][PADE]) ----
    const int seg = (EPI == 1) ? (n0 >> 9) : 0;     // 0=q 1=k 2=v when N=1536
    const float* bias = (EPI == 1) ? (seg == 0 ? bias0 : (seg == 1 ? bias1 : bias2)) : bias0;
    u16* dst = (EPI == 1) ? (seg == 0 ? out0 : (seg == 1 ? out1 : out2)) : out0;
    const int ldo = (EPI == 1) ? 512 : N;
    const int ncol0 = (EPI == 1) ? (n0 & 511) : n0;

#pragma unroll
    for (int pass = 0; pass < 2; ++pass) {
        if (wr == pass) {                           // 4 waves own rows pass*128..+127
#pragma unroll
            for (int fc = 0; fc < 4; ++fc) {
                const int col = wc * 64 + fc * 16 + lr;
                const float bv = bias[ncol0 + col];
#pragma unroll
                for (int fr = 0; fr < 8; ++fr)
#pragma unroll
                    for (int r = 0; r < 4; ++r) {
                        const int row = fr * 16 + (lg << 2) + r;    // local 0..127
                        smem[row * PADE + col] = f2b(acc[fr][fc][r] + bv);
                    }
            }
        }
        __syncthreads();
        const int rbase = m0 + (pass << 7);
#pragma unroll
        for (int it = 0; it < 8; ++it) {
            const int idx = it * 512 + tid;         // 0..4095
            const int row = idx >> 5;
            const int c8 = (idx & 31) << 3;
            s16x8 v8 = *(const s16x8*)(smem + row * PADE + c8);
            size_t gaddr = (size_t)(rbase + row) * ldo + ncol0 + c8;
            s16x8 o = v8;
            if constexpr (EPI == 1) {
                if (seg < 2) {
#pragma unroll
                    for (int e = 0; e < 8; ++e) {
                        float v = b2f((u16)v8[e]);
                        v = (v > 0.f) ? v + 1.f : __expf(v);   // elu+1
                        o[e] = (short)f2b(v);
                    }
                }
            } else if constexpr (EPI == 2) {
                s16x8 rv = *(const s16x8*)(resid + gaddr);
#pragma unroll
                for (int e = 0; e < 8; ++e)
                    o[e] = (short)f2b(b2f((u16)v8[e]) + b2f((u16)rv[e]));
            } else if constexpr (EPI == 3) {
#pragma unroll
                for (int e = 0; e < 8; ++e)
                    o[e] = (short)f2b(fmaxf(b2f((u16)v8[e]), 0.f));
            }
            *(s16x8*)(dst + gaddr) = o;
        }
        __syncthreads();
    }
}

// ---------------- kv einsum: kv[b,h,d,m] = sum_s k*v ; ksum[b,h,d] = sum_s k ----------
__global__ __launch_bounds__(256)
void k_kv(const u16* __restrict__ kb_, const u16* __restrict__ vb_,
          float* __restrict__ kvp, float* __restrict__ ksump) {
    __shared__ float sk[64 * 68], sv[64 * 68];
    int bh = blockIdx.x, b = bh >> 3, h = bh & 7;
    int ch = blockIdx.y;
    int tid = threadIdx.x;
    int d0 = (tid & 15) << 2, m0 = (tid >> 4) << 2;
    float acc[4][4] = {};
    float ks[4] = {0.f, 0.f, 0.f, 0.f};
    size_t gbase = ((size_t)b * SEQ_ + (size_t)ch * 1024) * DM_ + h * 64;

    for (int st = 0; st < 1024; st += 64) {
#pragma unroll
        for (int i = 0; i < 2; ++i) {
            int li = tid + (i << 8);
            int r = li >> 3, c8 = (li & 7) << 3;
            s16x8 kv_ = *(const s16x8*)(kb_ + gbase + (size_t)(st + r) * DM_ + c8);
            s16x8 vv_ = *(const s16x8*)(vb_ + gbase + (size_t)(st + r) * DM_ + c8);
#pragma unroll
            for (int e = 0; e < 8; ++e) {
                sk[r * 68 + c8 + e] = b2f((u16)kv_[e]);
                sv[r * 68 + c8 + e] = b2f((u16)vv_[e]);
            }
        }
        __syncthreads();
        for (int s = 0; s < 64; ++s) {
            f32x4 kd = *(const f32x4*)(sk + s * 68 + d0);
            f32x4 vm = *(const f32x4*)(sv + s * 68 + m0);
#pragma unroll
            for (int i = 0; i < 4; ++i)
#pragma unroll
                for (int j = 0; j < 4; ++j) acc[i][j] += kd[i] * vm[j];
            if ((tid >> 4) == 0) { ks[0] += kd[0]; ks[1] += kd[1]; ks[2] += kd[2]; ks[3] += kd[3]; }
        }
        __syncthreads();
    }
    float* kvo = kvp + ((size_t)ch * 64 + bh) * 4096;
#pragma unroll
    for (int i = 0; i < 4; ++i)
#pragma unroll
        for (int j = 0; j < 4; ++j) kvo[(d0 + i) * 64 + m0 + j] = acc[i][j];
    if ((tid >> 4) == 0) {
        float* kso = ksump + ((size_t)ch * 64 + bh) * 64;
#pragma unroll
        for (int e = 0; e < 4; ++e) kso[d0 + e] = ks[e];
    }
}

// ---------------- attention apply: a = (q . kv) / (q . ksum + eps) --------------------
__global__ __launch_bounds__(256)
void k_attn(const u16* __restrict__ qb_, const float* __restrict__ kvp,
            const float* __restrict__ ksump, u16* __restrict__ ab_) {
    __shared__ float skv[64 * 64];
    __shared__ float sq[64 * 65];
    __shared__ float sks[64];
    int tid = threadIdx.x;
    int bh = blockIdx.y, b = bh >> 3, h = bh & 7;
    int s0 = blockIdx.x << 6;

    for (int i = tid; i < 4096; i += 256) {
        float v = 0.f;
#pragma unroll
        for (int c = 0; c < 4; ++c) v += kvp[((size_t)c * 64 + bh) * 4096 + i];
        skv[i] = v;
    }
    if (tid < 64) {
        float v = 0.f;
#pragma unroll
        for (int c = 0; c < 4; ++c) v += ksump[((size_t)c * 64 + bh) * 64 + tid];
        sks[tid] = v;
    }
#pragma unroll
    for (int i = 0; i < 2; ++i) {
        int li = tid + (i << 8);
        int r = li >> 3, c8 = (li & 7) << 3;
        s16x8 v = *(const s16x8*)(qb_ + ((size_t)b * SEQ_ + s0 + r) * DM_ + h * 64 + c8);
#pragma unroll
        for (int e = 0; e < 8; ++e) sq[r * 65 + c8 + e] = b2f((u16)v[e]);
    }
    __syncthreads();

    int sl = tid >> 2, m0 = (tid & 3) << 4;
    float den = 0.f;
    for (int d = 0; d < 64; ++d) den += sq[sl * 65 + d] * sks[d];
    float z = 1.f / (den + 1e-6f);

    float acc[16] = {};
    for (int d = 0; d < 64; ++d) {
        float qv = sq[sl * 65 + d];
        const f32x4* kp = (const f32x4*)(skv + d * 64 + m0);
#pragma unroll
        for (int j4 = 0; j4 < 4; ++j4) {
            f32x4 kv4 = kp[j4];
#pragma unroll
            for (int e = 0; e < 4; ++e) acc[j4 * 4 + e] += qv * kv4[e];
        }
    }
    u16* op = ab_ + ((size_t)b * SEQ_ + s0 + sl) * DM_ + h * 64 + m0;
    s16x8 o0, o1;
#pragma unroll
    for (int e = 0; e < 8; ++e) o0[e] = (short)f2b(acc[e] * z);
#pragma unroll
    for (int e = 0; e < 8; ++e) o1[e] = (short)f2b(acc[8 + e] * z);
    *(s16x8*)op = o0;
    *(s16x8*)(op + 8) = o1;
}

// ---------------- LayerNorm over 512 (bf16 in -> bf16 out) ----------------------------
__global__ __launch_bounds__(256)
void k_ln(const u16* __restrict__ in, const float* __restrict__ g,
          const float* __restrict__ be, u16* __restrict__ xb) {
    int row = blockIdx.x * 4 + (threadIdx.x >> 6);
    int l = threadIdx.x & 63;
    s16x8 raw = *(const s16x8*)(in + (size_t)row * DM_ + l * 8);
    float x[8];
#pragma unroll
    for (int e = 0; e < 8; ++e) x[e] = b2f((u16)raw[e]);
    float sum = 0.f;
#pragma unroll
    for (int e = 0; e < 8; ++e) sum += x[e];
#pragma unroll
    for (int off = 32; off > 0; off >>= 1) sum += __shfl_xor(sum, off);
    float mu = sum * (1.f / DM_);
    float sq = 0.f;
#pragma unroll
    for (int e = 0; e < 8; ++e) { float d = x[e] - mu; sq += d * d; }
#pragma unroll
    for (int off = 32; off > 0; off >>= 1) sq += __shfl_xor(sq, off);
    float rs = rsqrtf(sq * (1.f / DM_) + 1e-5f);
    int c = l * 8;
    const f32x4* gp = (const f32x4*)(g + c);
    const f32x4* bp = (const f32x4*)(be + c);
    f32x4 g0 = gp[0], g1 = gp[1], e0 = bp[0], e1 = bp[1];
    s16x8 pk;
#pragma unroll
    for (int e = 0; e < 4; ++e) pk[e] = (short)f2b((x[e] - mu) * rs * g0[e] + e0[e]);
#pragma unroll
    for (int e = 0; e < 4; ++e) pk[4 + e] = (short)f2b((x[4 + e] - mu) * rs * g1[e] + e1[e]);
    *(s16x8*)(xb + (size_t)row * DM_ + c) = pk;
}

// ---------------- fused LN2 (layer 1) + final LN + Wout dot ---------------------------
__global__ __launch_bounds__(256)
void k_ln2f(const u16* __restrict__ in, const float* __restrict__ g2,
            const float* __restrict__ b2_, const float* __restrict__ gf,
            const float* __restrict__ bf_, const float* __restrict__ wout,
            const float* __restrict__ bout, float* __restrict__ out) {
    int row = blockIdx.x * 4 + (threadIdx.x >> 6);
    int l = threadIdx.x & 63;
    s16x8 raw = *(const s16x8*)(in + (size_t)row * DM_ + l * 8);
    float x[8];
#pragma unroll
    for (int e = 0; e < 8; ++e) x[e] = b2f((u16)raw[e]);
    float sum = 0.f;
#pragma unroll
    for (int e = 0; e < 8; ++e) sum += x[e];
#pragma unroll
    for (int off = 32; off > 0; off >>= 1) sum += __shfl_xor(sum, off);
    float mu = sum * (1.f / DM_);
    float sq = 0.f;
#pragma unroll
    for (int e = 0; e < 8; ++e) { float d = x[e] - mu; sq += d * d; }
#pragma unroll
    for (int off = 32; off > 0; off >>= 1) sq += __shfl_xor(sq, off);
    float rs = rsqrtf(sq * (1.f / DM_) + 1e-5f);
    int c = l * 8;
    float t[8];
#pragma unroll
    for (int e = 0; e < 8; ++e) t[e] = (x[e] - mu) * rs * g2[c + e] + b2_[c + e];
    float sum2 = 0.f;
#pragma unroll
    for (int e = 0; e < 8; ++e) sum2 += t[e];
#pragma unroll
    for (int off = 32; off > 0; off >>= 1) sum2 += __shfl_xor(sum2, off);
    float mu2 = sum2 * (1.f / DM_);
    float sq2 = 0.f;
#pragma unroll
    for (int e = 0; e < 8; ++e) { float d = t[e] - mu2; sq2 += d * d; }
#pragma unroll
    for (int off = 32; off > 0; off >>= 1) sq2 += __shfl_xor(sq2, off);
    float rs2 = rsqrtf(sq2 * (1.f / DM_) + 1e-5f);
    float p = 0.f;
#pragma unroll
    for (int e = 0; e < 8; ++e)
        p += ((t[e] - mu2) * rs2 * gf[c + e] + bf_[c + e]) * wout[c + e];
#pragma unroll
    for (int off = 32; off > 0; off >>= 1) p += __shfl_xor(p, off);
    if (l == 0) out[row] = p + bout[0];
}

// =======================================================================================
extern "C" void kernel_launch(void* const* d_in, const int* in_sizes, int n_in,
                              void* d_out, int out_size, void* d_ws, size_t ws_size,
                              hipStream_t stream) {
    const float* emb   = (const float*)d_in[0];
    const float* W0    = (const float*)d_in[1];
    const float* b0    = (const float*)d_in[2];
    const float* Wq    = (const float*)d_in[3];
    const float* bq    = (const float*)d_in[4];
    const float* Wk    = (const float*)d_in[5];
    const float* bk    = (const float*)d_in[6];
    const float* Wv    = (const float*)d_in[7];
    const float* bv    = (const float*)d_in[8];
    const float* Wo    = (const float*)d_in[9];
    const float* bo    = (const float*)d_in[10];
    const float* ln1s  = (const float*)d_in[11];
    const float* ln1b  = (const float*)d_in[12];
    const float* W1    = (const float*)d_in[13];
    const float* b1    = (const float*)d_in[14];
    const float* W2    = (const float*)d_in[15];
    const float* b2    = (const float*)d_in[16];
    const float* ln2s  = (const float*)d_in[17];
    const float* ln2b  = (const float*)d_in[18];
    const float* lnfs  = (const float*)d_in[19];
    const float* lnfb  = (const float*)d_in[20];
    const float* Wout  = (const float*)d_in[21];
    const float* bout  = (const float*)d_in[22];
    float* out = (float*)d_out;

    char* ws = (char*)d_ws;
    size_t off = 0;
    auto alloc = [&](size_t bytes) -> void* {
        void* p = ws + off;
        off += (bytes + 255) & ~(size_t)255;
        return p;
    };
    u16* xb   = (u16*)alloc((size_t)BS_ * DM_ * 2);    // 32MB  x (bf16 stream)
    u16* qb   = (u16*)alloc((size_t)BS_ * DM_ * 2);    // 32MB  (rb aliases qb)
    u16* kb   = (u16*)alloc((size_t)BS_ * DM_ * 2);    // 32MB
    u16* vb   = (u16*)alloc((size_t)BS_ * DM_ * 2);    // 32MB
    float* kvp   = (float*)alloc((size_t)4 * 64 * 4096 * 4);
    float* ksump = (float*)alloc((size_t)4 * 64 * 64 * 4);
    u16* wp   = (u16*)alloc((size_t)4521984 * 2);      // weight pool ~9MB

    u16* rb   = qb;    // residual r (written after qb dead)
    u16* ab   = vb;    // attn output (written after vb consumed)
    u16* h1b  = kb;    // 64MB FF hidden = kb+vb regions
    u16* embp = kb;    // 40MB emb bf16 padded = kb+vb regions (dead before QKV)

    u16* W0t  = wp;                          // [512][640]
    u16* Wqkv = wp + 327680;                 // per layer [1536][512]
    u16* Wot  = Wqkv + 2 * 786432;           // per layer [512][512]
    u16* W1t  = Wot + 2 * 262144;            // per layer [1024][512]
    u16* W2t  = W1t + 2 * 524288;            // per layer [512][1024]

    k_tr_all<<<4416, dim3(32, 8), 0, stream>>>(W0, Wq, Wk, Wv, Wo, W1, W2,
                                               W0t, Wqkv, Wot, W1t, W2t);
    k_emb<<<2560, 256, 0, stream>>>(emb, embp);

    // x = emb @ W0 + b0
    k_gemm<0><<<256, 512, 0, stream>>>(embp, W0t, b0, nullptr, nullptr,
                                       nullptr, xb, nullptr, nullptr, BS_, DM_, FINP_, 2);

    for (int l = 0; l < 2; ++l) {
        // fused QKV: N=1536, feat(elu+1) on q,k
        k_gemm<1><<<768, 512, 0, stream>>>(xb, Wqkv + (size_t)l * 786432,
                                           bq + l * 512, bk + l * 512, bv + l * 512,
                                           nullptr, qb, kb, vb, BS_, 1536, 512, 6);
        k_kv<<<dim3(64, 4), 256, 0, stream>>>(kb, vb, kvp, ksump);
        k_attn<<<dim3(64, 64), 256, 0, stream>>>(qb, kvp, ksump, ab);
        // r = x + a@Wo + bo
        k_gemm<2><<<256, 512, 0, stream>>>(ab, Wot + (size_t)l * 262144,
                                           bo + l * 512, nullptr, nullptr,
                                           xb, rb, nullptr, nullptr, BS_, 512, 512, 2);
        k_ln<<<8192, 256, 0, stream>>>(rb, ln1s + l * 512, ln1b + l * 512, xb);
        // h = relu(x@W1+b1)
        k_gemm<3><<<512, 512, 0, stream>>>(xb, W1t + (size_t)l * 524288,
                                           b1 + l * 1024, nullptr, nullptr,
                                           nullptr, h1b, nullptr, nullptr, BS_, 1024, 512, 4);
        // r = x + h@W2 + b2
        k_gemm<2><<<256, 512, 0, stream>>>(h1b, W2t + (size_t)l * 524288,
                                           b2 + l * 512, nullptr, nullptr,
                                           xb, rb, nullptr, nullptr, BS_, 512, 1024, 2);
        if (l == 0)
            k_ln<<<8192, 256, 0, stream>>>(rb, ln2s, ln2b, xb);
        else
            k_ln2f<<<8192, 256, 0, stream>>>(rb, ln2s + 512, ln2b + 512,
                                             lnfs, lnfb, Wout, bout, out);
    }
}